// Round 5
// baseline (103.932 us; speedup 1.0000x reference)
//
#include <hip/hip_runtime.h>
#include <hip/hip_bf16.h>
#include <math.h>

#define H    16
#define HKV  4
#define G    4
#define NN   2048
#define D    64
#define HID  1024
#define CB   16
#define W    128
#define NSEL 4
#define WIN  64
#define NEGV -1e10f
#define SCALE 0.125f

typedef __attribute__((ext_vector_type(4))) float f32x4;
typedef __attribute__((ext_vector_type(4))) short short4v;
typedef __attribute__((ext_vector_type(8))) short short8v;

__device__ inline short f2b(float x){
    __hip_bfloat16 h = __float2bfloat16(x);
    return *reinterpret_cast<short*>(&h);
}
__device__ inline float b2f(short s){
    unsigned u = ((unsigned)(unsigned short)s) << 16;
    return __builtin_bit_cast(float, u);
}
__device__ inline short8v cvt8(f32x4 a, f32x4 b){
    short8v r;
    r[0]=f2b(a[0]); r[1]=f2b(a[1]); r[2]=f2b(a[2]); r[3]=f2b(a[3]);
    r[4]=f2b(b[0]); r[5]=f2b(b[1]); r[6]=f2b(b[2]); r[7]=f2b(b[3]);
    return r;
}
#define SWZ(byte, row) ((byte) ^ (((row)&7)<<4))
#define MFMA(a,b,c) __builtin_amdgcn_mfma_f32_16x16x32_bf16(a,b,c,0,0,0)

__device__ inline float wave_sum(float x){ for(int o=32;o;o>>=1) x += __shfl_xor(x,o); return x; }
__device__ inline float wave_max(float x){ for(int o=32;o;o>>=1) x = fmaxf(x,__shfl_xor(x,o)); return x; }

__device__ inline f32x4 vmax4(f32x4 a, f32x4 b){
    f32x4 r; r[0]=fmaxf(a[0],b[0]); r[1]=fmaxf(a[1],b[1]); r[2]=fmaxf(a[2],b[2]); r[3]=fmaxf(a[3],b[3]); return r;
}
__device__ inline f32x4 shflx4(f32x4 x, int o){
    f32x4 r; r[0]=__shfl_xor(x[0],o); r[1]=__shfl_xor(x[1],o); r[2]=__shfl_xor(x[2],o); r[3]=__shfl_xor(x[3],o); return r;
}
__device__ inline f32x4 exp4(f32x4 x){
    f32x4 r; r[0]=expf(x[0]); r[1]=expf(x[1]); r[2]=expf(x[2]); r[3]=expf(x[3]); return r;
}

// ---------------------------------------------------------------------------
// fused prep (unchanged from round 4)
__device__ inline void conv_seg(const float* __restrict__ src, short* __restrict__ dst,
                                int b, int t){
    size_t idx = (size_t)b*1024 + t*4;
    f32x4 a = *(const f32x4*)(src + idx);
    short4v r; r[0]=f2b(a[0]); r[1]=f2b(a[1]); r[2]=f2b(a[2]); r[3]=f2b(a[3]);
    *(short4v*)(dst + idx) = r;
}

__global__ __launch_bounds__(256) void k_prep(
    const float* __restrict__ q, const float* __restrict__ hidden,
    const float* __restrict__ combine_w, const float* __restrict__ combiner_w,
    const float* __restrict__ k, const float* __restrict__ v,
    const float* __restrict__ memkv, const float* __restrict__ ksc, const float* __restrict__ vsc,
    short* __restrict__ qb, short* __restrict__ hb, short* __restrict__ wb,
    short* __restrict__ cwb, short* __restrict__ kb16, short* __restrict__ vT,
    short* __restrict__ ckb, short* __restrict__ cvtg)
{
    int b = blockIdx.x, t = threadIdx.x;
    if (b < 2048){ conv_seg(q, qb, b, t); return; }
    b -= 2048;
    if (b < 2048){ conv_seg(hidden, hb, b, t); return; }
    b -= 2048;
    if (b < 1024){ conv_seg(combine_w, wb, b, t); return; }
    b -= 1024;
    if (b < 48){ conv_seg(combiner_w, cwb, b, t); return; }
    b -= 48;
    if (b < 512){ conv_seg(k, kb16, b, t); return; }
    b -= 512;
    if (b < 128){
        __shared__ float tl[64][65];
        int hk = b>>5, i0 = (b&31)*64;
        for (int u=0;u<4;u++){
            int cid = t + 256*u; int r = cid>>4, ch = cid&15;
            f32x4 a = *(const f32x4*)(v + ((size_t)(hk*NN + i0 + r))*D + ch*4);
            tl[r][ch*4+0]=a[0]; tl[r][ch*4+1]=a[1]; tl[r][ch*4+2]=a[2]; tl[r][ch*4+3]=a[3];
        }
        __syncthreads();
        int d = t>>2, qd = t&3;
        short8v p0, p1;
        #pragma unroll
        for (int e=0;e<8;e++) p0[e] = f2b(tl[qd*16+e][d]);
        #pragma unroll
        for (int e=0;e<8;e++) p1[e] = f2b(tl[qd*16+8+e][d]);
        short* dst = vT + ((size_t)(hk*64 + d))*NN + i0 + qd*16;
        *(short8v*)dst = p0;
        *(short8v*)(dst+8) = p1;
        return;
    }
    b -= 128;
    {
        int j = b;
        int hk = t>>6, d = t&63;
        if (j > 128){
            if (j < 144) ckb[((size_t)(hk*144 + j))*64 + d] = 0;
            cvtg[((size_t)(hk*64 + d))*160 + j] = 0;
            return;
        }
        float xk, xv;
        if (j==0){ xk = memkv[(0*HKV+hk)*D + d]; xv = memkv[(HKV+hk)*D + d]; }
        else {
            int jb = j-1;
            const float* kp = k + ((size_t)(hk*NN + jb*CB))*D + d;
            const float* vp = v + ((size_t)(hk*NN + jb*CB))*D + d;
            float sk=0.f, sv=0.f;
            #pragma unroll
            for (int tt=0;tt<CB;tt++){ sk += kp[tt*D]; sv += vp[tt*D]; }
            xk = sk*(1.0f/CB); xv = sv*(1.0f/CB);
            float msk = wave_sum(xk*xk)*(1.0f/D);
            float msv = wave_sum(xv*xv)*(1.0f/D);
            xk = xk*rsqrtf(msk+1e-6f)*ksc[d];
            xv = xv*rsqrtf(msv+1e-6f)*vsc[d];
        }
        ckb[((size_t)(hk*144 + j))*64 + d] = f2b(xk);
        cvtg[((size_t)(hk*64 + d))*160 + j] = f2b(xv);
    }
}

// ---------------------------------------------------------------------------
// compressed attention + importance + top-k. Block = (hk, 16 tokens), 4 waves.
// M=64 rows (token*4+head), N=144 (129 valid), K=64. Dynamic LDS 76032 B -> 2 blocks/CU.
__global__ __launch_bounds__(256) void k_cattn(
    const short* __restrict__ qb, const short* __restrict__ ckb, const short* __restrict__ cvt_g,
    short* __restrict__ outc, int* __restrict__ selidx)
{
    extern __shared__ char smem[];
    char* aq  = smem;                      // 64 * 128 = 8192
    char* ckl = smem + 8192;               // 144 * 128 = 18432  (ends 26624)
    char* cvl = smem + 26624;              // 64 * 320 = 20480   (ends 47104)
    char* pl  = smem + 47104;              // 64 * 320 = 20480   (ends 67584)
    float* impl = (float*)(smem + 67584);  // 16*128 f32 = 8192  (ends 75776)
    float* psl  = (float*)(smem + 75776);  // 64 f32 = 256       (ends 76032)
    int i0 = blockIdx.x*16, hk = blockIdx.y, t = threadIdx.x;

    // stage Q: 64 rows (row = tok*4+head), 8 ch of 16 B
    for (int u=0;u<2;u++){
        int cid = t + 256*u; int row = cid>>3, ch = cid&7;
        const short* src = qb + ((size_t)((hk*G + (row&3))*NN + i0 + (row>>2)))*D + ch*8;
        *(short8v*)(aq + SWZ(row*128 + ch*16, row)) = *(const short8v*)src;
    }
    // stage CK: 144 rows
    for (int u=0;u<5;u++){
        int cid = t + 256*u;
        if (cid < 1152){
            int row = cid>>3, ch = cid&7;
            const short* src = ckb + ((size_t)(hk*144 + row))*64 + ch*8;
            *(short8v*)(ckl + SWZ(row*128 + ch*16, row)) = *(const short8v*)src;
        }
    }
    // stage CV^T: 64 rows x 20 slots (=160 cols, pad cols zeroed in global)
    for (int u=0;u<5;u++){
        int cid = t + 256*u;   // 0..1279
        int row = cid/20, ch = cid%20;
        *(short8v*)(cvl + SWZ(row*320 + ch*16, row)) =
            *(const short8v*)(cvt_g + ((size_t)(hk*64 + row))*160 + ch*8);
    }
    // zero P pad cols 144..159 (bytes 288..319), 64 rows x 2 slots
    if (t < 128){
        int row = t>>1, sl = t&1;
        *(short8v*)(pl + SWZ(row*320 + 288 + sl*16, row)) = (short8v)0;
    }
    __syncthreads();

    int w = t>>6, lane = t&63, c = lane&15, lg = lane>>4;
    f32x4 acc[9];
    #pragma unroll
    for (int ct=0;ct<9;ct++) acc[ct] = (f32x4)0.f;

    #pragma unroll
    for (int ks=0;ks<2;ks++){
        int arow = w*16 + c;
        short8v af = *(short8v*)(aq + SWZ(arow*128 + ks*64 + lg*16, arow));
        #pragma unroll
        for (int ct=0;ct<9;ct++){
            int row = ct*16 + c;
            short8v bf = *(short8v*)(ckl + SWZ(row*128 + ks*64 + lg*16, row));
            acc[ct] = MFMA(af, bf, acc[ct]);
        }
    }

    // scale + mask + importance + softmax + write P
    {
        int tloc = w*4 + lg;               // token within tile (regs = 4 heads)
        int ii = i0 + tloc;
        #pragma unroll
        for (int ct=0;ct<9;ct++){
            int j = ct*16 + c;
            bool vis = (j==0) || (j<=128 && j*16 <= ii);
            f32x4 s = acc[ct]*SCALE;
            if (!vis){ s[0]=NEGV; s[1]=NEGV; s[2]=NEGV; s[3]=NEGV; }
            acc[ct] = s;
        }
        #pragma unroll
        for (int ct=0;ct<9;ct++){
            int j = ct*16 + c;
            if (j>=1 && j<=128){
                f32x4 s = acc[ct];
                impl[tloc*128 + (j-1)] = 0.25f*(s[0]+s[1]+s[2]+s[3]);
            }
        }
        f32x4 mx = acc[0];
        #pragma unroll
        for (int ct=1;ct<9;ct++) mx = vmax4(mx, acc[ct]);
        #pragma unroll
        for (int o=1;o<16;o<<=1) mx = vmax4(mx, shflx4(mx,o));
        f32x4 sum = (f32x4)0.f;
        #pragma unroll
        for (int ct=0;ct<9;ct++){ acc[ct] = exp4(acc[ct]-mx); sum += acc[ct]; }
        #pragma unroll
        for (int o=1;o<16;o<<=1) sum += shflx4(sum,o);
        #pragma unroll
        for (int ct=0;ct<9;ct++){
            #pragma unroll
            for (int reg=0;reg<4;reg++){
                int row = w*16 + lg*4 + reg;
                *(short*)(pl + SWZ(row*320 + (ct*16+c)*2, row)) = f2b(acc[ct][reg]);
            }
        }
        if (c==0){
            #pragma unroll
            for (int reg=0;reg<4;reg++) psl[w*16 + lg*4 + reg] = sum[reg];
        }
    }
    __syncthreads();

    // top-k: 4 tokens per wave
    #pragma unroll 1
    for (int s4=0;s4<4;s4++){
        int tt = w*4 + s4;
        float v0 = impl[tt*128 + lane];
        float v1 = impl[tt*128 + 64 + lane];
        int sel[4];
        #pragma unroll
        for (int r4=0;r4<4;r4++){
            float bv; int bj;
            if (v1 > v0){ bv=v1; bj=lane+64; } else { bv=v0; bj=lane; }
            #pragma unroll
            for (int o=32;o;o>>=1){
                float ov = __shfl_xor(bv,o);
                int oj = __shfl_xor(bj,o);
                if (ov > bv || (ov==bv && oj<bj)){ bv=ov; bj=oj; }
            }
            sel[r4]=bj;
            if (bj==lane) v0 = -INFINITY;
            else if (bj==lane+64) v1 = -INFINITY;
        }
        if (lane==0){
            int* sp = selidx + ((size_t)(hk*NN + i0 + tt))*NSEL;
            sp[0]=sel[0]; sp[1]=sel[1]; sp[2]=sel[2]; sp[3]=sel[3];
        }
    }

    // PV
    f32x4 pv[4];
    #pragma unroll
    for (int ctd=0;ctd<4;ctd++) pv[ctd] = (f32x4)0.f;
    #pragma unroll
    for (int ks=0;ks<5;ks++){
        int arow = w*16 + c;
        short8v pf = *(short8v*)(pl + SWZ(arow*320 + ks*64 + lg*16, arow));
        #pragma unroll
        for (int ctd=0;ctd<4;ctd++){
            int row = ctd*16 + c;
            short8v bf = *(short8v*)(cvl + SWZ(row*320 + ks*64 + lg*16, row));
            pv[ctd] = MFMA(pf, bf, pv[ctd]);
        }
    }
    #pragma unroll
    for (int ctd=0;ctd<4;ctd++)
        #pragma unroll
        for (int reg=0;reg<4;reg++){
            int row = w*16 + lg*4 + reg;
            float inv = 1.0f/psl[row];
            int hh = hk*G + reg;
            int ii = i0 + (row>>2);
            outc[((size_t)(hh*NN + ii))*D + ctd*16 + c] = f2b(pv[ctd][reg]*inv);
        }
}

// ---------------------------------------------------------------------------
// fused: selattn (blocks 0..8191) + swin (8192..8703) + gates (8704..8831).
__global__ __launch_bounds__(256) void k_att3(
    const float* __restrict__ q, const float* __restrict__ k, const float* __restrict__ v,
    const int* __restrict__ selidx, short* __restrict__ outf,
    const short* __restrict__ qb, const short* __restrict__ kb16, const short* __restrict__ vT,
    short* __restrict__ outs,
    const short* __restrict__ hb, const short* __restrict__ cwb, float* __restrict__ gpart)
{
    __shared__ char smem[57600];
    int b = blockIdx.x, t = threadIdx.x;

    if (b < 8192){
        // ---------------- selected-block attention, fp32 ----------------
        char* ksl = smem;                     // 64*256 = 16384
        float* vs = (float*)(smem + 16384);   // 64*64*4 = 16384
        float* qs = (float*)(smem + 32768);   // 256*4 = 1024
        float* ps = (float*)(smem + 33792);   // 256*4 = 1024
        int* sel_s = (int*)(smem + 34816);    // 4 ints
        int hk = b >> 11, i = b & 2047;
        if (t < 4) sel_s[t] = selidx[((size_t)(hk*NN + i))*NSEL + t];
        __syncthreads();
        {
            int hh = t>>6, d = t&63;
            qs[t] = q[((size_t)((hk*G+hh)*NN + i))*D + d];
        }
        for (int u=0;u<4;u++){
            int cid = t + 256*u; int row = cid>>4, ch = cid&15;
            int pos = sel_s[row>>4]*CB + (row&15);
            f32x4 kk = *(const f32x4*)(k + ((size_t)(hk*NN + pos))*D + ch*4);
            *(f32x4*)(ksl + SWZ(row*256 + ch*16, row)) = kk;
            f32x4 vv = *(const f32x4*)(v + ((size_t)(hk*NN + pos))*D + ch*4);
            *(f32x4*)((char*)vs + row*256 + ch*16) = vv;
        }
        __syncthreads();
        int wv = t>>6, lane = t&63;
        f32x4 qr[16];
        #pragma unroll
        for (int d4=0;d4<16;d4++) qr[d4] = *(f32x4*)(qs + wv*64 + d4*4);
        int pos_l = sel_s[lane>>4]*CB + (lane&15);
        float s = 0.f;
        #pragma unroll
        for (int d4=0;d4<16;d4++){
            f32x4 kk = *(f32x4*)(ksl + SWZ(lane*256 + d4*16, lane));
            s += qr[d4][0]*kk[0] + qr[d4][1]*kk[1] + qr[d4][2]*kk[2] + qr[d4][3]*kk[3];
        }
        s *= SCALE;
        if (pos_l > i) s = NEGV;
        float m = wave_max(s);
        float p = expf(s - m);
        float psum = wave_sum(p);
        ps[wv*64 + lane] = p;
        __syncthreads();
        int jg = lane>>4, dg = lane&15;
        f32x4 partial = (f32x4)0.f;
        #pragma unroll
        for (int jj=0;jj<16;jj++){
            int j = jg*16 + jj;
            float pw = ps[wv*64 + j];
            f32x4 vv = *(f32x4*)(vs + j*64 + dg*4);
            partial += vv * pw;
        }
        partial += shflx4(partial, 16);
        partial += shflx4(partial, 32);
        if (lane < 16){
            float inv = 1.0f/psum;
            short4v r;
            r[0]=f2b(partial[0]*inv); r[1]=f2b(partial[1]*inv);
            r[2]=f2b(partial[2]*inv); r[3]=f2b(partial[3]*inv);
            *(short4v*)(outf + ((size_t)((hk*G+wv)*NN + i))*D + dg*4) = r;
        }
        return;
    }
    if (b < 8704){
        // ---------------- sliding-window attention, bf16 MFMA ----------------
        int idx = b - 8192;
        char* aq = smem;                   // 8192
        char* kb = smem + 8192;            // 16384 (ends 24576)
        char* vl = smem + 24576;           // 16384 (ends 40960)
        char* pl = smem + 40960;           // 16384 (ends 57344)
        float* psl = (float*)(smem + 57344); // 256
        int i0 = (idx & 31)*64, h = idx >> 5;
        int hk = h >> 2;
        int pa = i0 - 64;
        for (int u=0;u<2;u++){
            int cid = t + 256*u; int row = cid>>3, ch = cid&7;
            *(short8v*)(aq + SWZ(row*128 + ch*16, row)) =
                *(const short8v*)(qb + ((size_t)(h*NN + i0 + row))*D + ch*8);
        }
        for (int u=0;u<4;u++){
            int cid = t + 256*u; int row = cid>>3, ch = cid&7;
            int pos = pa + row; pos = pos < 0 ? 0 : pos;
            *(short8v*)(kb + SWZ(row*128 + ch*16, row)) =
                *(const short8v*)(kb16 + ((size_t)(hk*NN + pos))*D + ch*8);
        }
        for (int u=0;u<4;u++){
            int cid = t + 256*u; int d = cid>>4, ch = cid&15;
            int ps0 = pa + ch*8;
            short8v val;
            const short* src = vT + ((size_t)(hk*64 + d))*NN + ps0;
            if (ps0 >= 0) val = *(const short8v*)src;
            else {
                #pragma unroll
                for (int e=0;e<8;e++){ int pp = ps0+e; pp = pp<0?0:pp; val[e] = vT[((size_t)(hk*64+d))*NN + pp]; }
            }
            *(short8v*)(vl + SWZ(d*256 + ch*16, d)) = val;
        }
        __syncthreads();
        int w = t>>6, lane = t&63, c = lane&15, lg = lane>>4;
        f32x4 acc[8];
        #pragma unroll
        for (int ct=0;ct<8;ct++) acc[ct] = (f32x4)0.f;
        #pragma unroll
        for (int ks=0;ks<2;ks++){
            int arow = w*16 + c;
            short8v af = *(short8v*)(aq + SWZ(arow*128 + ks*64 + lg*16, arow));
            #pragma unroll
            for (int ct=0;ct<8;ct++){
                int brow = ct*16 + c;
                short8v bf = *(short8v*)(kb + SWZ(brow*128 + ks*64 + lg*16, brow));
                acc[ct] = MFMA(af, bf, acc[ct]);
            }
        }
        #pragma unroll
        for (int ct=0;ct<8;ct++){
            int j = ct*16 + c;
            #pragma unroll
            for (int reg=0;reg<4;reg++){
                int tl = w*16 + lg*4 + reg;
                bool vis = (j >= tl+1) && (j <= tl+64) && (pa + j >= 0);
                float s = acc[ct][reg]*SCALE;
                acc[ct][reg] = vis ? s : NEGV;
            }
        }
        f32x4 mx = acc[0];
        #pragma unroll
        for (int ct=1;ct<8;ct++) mx = vmax4(mx, acc[ct]);
        #pragma unroll
        for (int o=1;o<16;o<<=1) mx = vmax4(mx, shflx4(mx,o));
        f32x4 sum = (f32x4)0.f;
        #pragma unroll
        for (int ct=0;ct<8;ct++){ acc[ct] = exp4(acc[ct]-mx); sum += acc[ct]; }
        #pragma unroll
        for (int o=1;o<16;o<<=1) sum += shflx4(sum,o);
        #pragma unroll
        for (int ct=0;ct<8;ct++){
            #pragma unroll
            for (int reg=0;reg<4;reg++){
                int row = w*16 + lg*4 + reg;
                *(short*)(pl + SWZ(row*256 + (ct*16+c)*2, row)) = f2b(acc[ct][reg]);
            }
        }
        if (c==0){
            #pragma unroll
            for (int reg=0;reg<4;reg++) psl[w*16+lg*4+reg] = sum[reg];
        }
        __syncthreads();
        f32x4 pv[4];
        #pragma unroll
        for (int ctd=0;ctd<4;ctd++) pv[ctd] = (f32x4)0.f;
        #pragma unroll
        for (int ks=0;ks<4;ks++){
            int arow = w*16 + c;
            short8v pf = *(short8v*)(pl + SWZ(arow*256 + ks*64 + lg*16, arow));
            #pragma unroll
            for (int ctd=0;ctd<4;ctd++){
                int brow = ctd*16 + c;
                short8v bf = *(short8v*)(vl + SWZ(brow*256 + ks*64 + lg*16, brow));
                pv[ctd] = MFMA(pf, bf, pv[ctd]);
            }
        }
        #pragma unroll
        for (int ctd=0;ctd<4;ctd++)
            #pragma unroll
            for (int reg=0;reg<4;reg++){
                int row = w*16 + lg*4 + reg;
                float inv = 1.0f/psl[row];
                outs[((size_t)(h*NN + i0 + row))*D + ctd*16 + c] = f2b(pv[ctd][reg]*inv);
            }
        return;
    }
    {
        // ---------------- gates split-K partial GEMM ----------------
        int idx = b - 8704;
        char* ha = smem;                  // 8192
        char* bl = smem + 8192;           // 6144
        int i0 = (idx & 31)*64, ky = idx >> 5;
        int w = t>>6, lane = t&63, c = lane&15, lg = lane>>4;
        f32x4 acc[3];
        #pragma unroll
        for (int ct=0;ct<3;ct++) acc[ct] = (f32x4)0.f;
        for (int kc=0;kc<4;kc++){
            int kbase = ky*256 + kc*64;
            if (kc) __syncthreads();
            for (int u=0;u<2;u++){
                int cid = t + 256*u; int row = cid>>3, ch = cid&7;
                *(short8v*)(ha + SWZ(row*128 + ch*16, row)) =
                    *(const short8v*)(hb + (size_t)(i0+row)*HID + kbase + ch*8);
            }
            for (int u=0;u<2;u++){
                int cid = t + 256*u;
                if (cid < 384){
                    int row = cid>>3, ch = cid&7;
                    *(short8v*)(bl + SWZ(row*128 + ch*16, row)) =
                        *(const short8v*)(cwb + (size_t)row*HID + kbase + ch*8);
                }
            }
            __syncthreads();
            #pragma unroll
            for (int ks=0;ks<2;ks++){
                int arow = w*16 + c;
                short8v af = *(short8v*)(ha + SWZ(arow*128 + ks*64 + lg*16, arow));
                #pragma unroll
                for (int ct=0;ct<3;ct++){
                    int brow = ct*16 + c;
                    short8v bf = *(short8v*)(bl + SWZ(brow*128 + ks*64 + lg*16, brow));
                    acc[ct] = MFMA(af, bf, acc[ct]);
                }
            }
        }
        #pragma unroll
        for (int ct=0;ct<3;ct++)
            #pragma unroll
            for (int reg=0;reg<4;reg++){
                int row = w*16 + lg*4 + reg;
                gpart[((size_t)ky*NN + i0 + row)*48 + ct*16 + c] = acc[ct][reg];
            }
    }
}

// ---------------------------------------------------------------------------
// gated combine -> comb bf16 [N][HID]
__global__ __launch_bounds__(256) void k_comb(
    const short* __restrict__ outc, const short* __restrict__ outf, const short* __restrict__ outs_,
    const float* __restrict__ gpart, const float* __restrict__ cb, short* __restrict__ comb)
{
    __shared__ float gs[48];
    int i = blockIdx.x, t = threadIdx.x;
    if (t < 48){
        float s = gpart[(size_t)0*NN*48 + i*48 + t] + gpart[(size_t)1*NN*48 + i*48 + t]
                + gpart[(size_t)2*NN*48 + i*48 + t] + gpart[(size_t)3*NN*48 + i*48 + t] + cb[t];
        gs[t] = 1.0f/(1.0f+expf(-s));
    }
    __syncthreads();
    int hh = t>>4, d0 = (t&15)*4;
    float g0 = gs[hh*3], g1 = gs[hh*3+1], g2 = gs[hh*3+2];
    size_t off = ((size_t)(hh*NN + i))*D + d0;
    short4v a = *(const short4v*)(outc + off);
    short4v b = *(const short4v*)(outf + off);
    short4v cc = *(const short4v*)(outs_ + off);
    short4v r;
    #pragma unroll
    for (int e=0;e<4;e++) r[e] = f2b(g0*b2f(a[e]) + g1*b2f(b[e]) + g2*b2f(cc[e]));
    *(short4v*)(comb + (size_t)i*HID + t*4) = r;
}

// ---------------------------------------------------------------------------
// out = comb (bf16 2048x1024) @ wb^T (bf16 1024x1024), f32 out. 64x64 tile, dbuf.
__global__ __launch_bounds__(256) void k_gemm(
    const short* __restrict__ A, const short* __restrict__ Bw, float* __restrict__ out)
{
    __shared__ char ab[2][64*128];
    __shared__ char bb[2][64*128];
    int m0 = blockIdx.x*64, n0 = blockIdx.y*64, t = threadIdx.x;
    int w = t>>6, lane = t&63, c = lane&15, lg = lane>>4;
    int r0 = t>>3, ch0 = t&7;
    f32x4 acc[4];
    #pragma unroll
    for (int ct=0;ct<4;ct++) acc[ct] = (f32x4)0.f;
    const short* Ap = A  + (size_t)(m0+r0)*HID + ch0*8;
    const short* Bp = Bw + (size_t)(n0+r0)*HID + ch0*8;
    short8v ra0 = *(const short8v*)(Ap);
    short8v ra1 = *(const short8v*)(Ap + 32*HID);
    short8v rb0 = *(const short8v*)(Bp);
    short8v rb1 = *(const short8v*)(Bp + 32*HID);
    for (int kc=0;kc<16;kc++){
        char* abuf = ab[kc&1];
        char* bbuf = bb[kc&1];
        *(short8v*)(abuf + SWZ(r0*128 + ch0*16, r0)) = ra0;
        *(short8v*)(abuf + SWZ((r0+32)*128 + ch0*16, r0+32)) = ra1;
        *(short8v*)(bbuf + SWZ(r0*128 + ch0*16, r0)) = rb0;
        *(short8v*)(bbuf + SWZ((r0+32)*128 + ch0*16, r0+32)) = rb1;
        __syncthreads();
        if (kc < 15){
            const short* Ap2 = Ap + (kc+1)*64;
            const short* Bp2 = Bp + (kc+1)*64;
            ra0 = *(const short8v*)(Ap2);
            ra1 = *(const short8v*)(Ap2 + 32*HID);
            rb0 = *(const short8v*)(Bp2);
            rb1 = *(const short8v*)(Bp2 + 32*HID);
        }
        #pragma unroll
        for (int ks=0;ks<2;ks++){
            int arow = w*16 + c;
            short8v af = *(short8v*)(abuf + SWZ(arow*128 + ks*64 + lg*16, arow));
            #pragma unroll
            for (int ct=0;ct<4;ct++){
                int brow = ct*16 + c;
                short8v bf = *(short8v*)(bbuf + SWZ(brow*128 + ks*64 + lg*16, brow));
                acc[ct] = MFMA(af, bf, acc[ct]);
            }
        }
    }
    #pragma unroll
    for (int ct=0;ct<4;ct++)
        #pragma unroll
        for (int reg=0;reg<4;reg++){
            int row = w*16 + lg*4 + reg;
            out[((size_t)(m0+row))*HID + n0 + ct*16 + c] = acc[ct][reg];
        }
}

// ---------------------------------------------------------------------------
extern "C" void kernel_launch(void* const* d_in, const int* in_sizes, int n_in,
                              void* d_out, int out_size, void* d_ws, size_t ws_size,
                              hipStream_t stream)
{
    const float* hidden     = (const float*)d_in[0];
    const float* q          = (const float*)d_in[1];
    const float* k          = (const float*)d_in[2];
    const float* v          = (const float*)d_in[3];
    const float* memkv      = (const float*)d_in[4];
    const float* ksc        = (const float*)d_in[5];
    const float* vsc        = (const float*)d_in[6];
    const float* combiner_w = (const float*)d_in[7];
    const float* combiner_b = (const float*)d_in[8];
    const float* combine_w  = (const float*)d_in[9];
    float* out = (float*)d_out;

    char* p = (char*)d_ws;
    short* ckb  = (short*)p; p += (size_t)HKV*144*64*2;
    short* cvtg = (short*)p; p += (size_t)HKV*64*160*2;
    short* qbg  = (short*)p; p += (size_t)H*NN*D*2;
    short* hbg  = (short*)p; p += (size_t)NN*HID*2;
    short* wbg  = (short*)p; p += (size_t)HID*HID*2;
    short* cwbg = (short*)p; p += (size_t)48*HID*2;
    short* kbg  = (short*)p; p += (size_t)HKV*NN*D*2;
    short* vTg  = (short*)p; p += (size_t)HKV*64*NN*2;
    short* outc = (short*)p; p += (size_t)H*NN*D*2;
    short* outf = (short*)p; p += (size_t)H*NN*D*2;
    short* outs = (short*)p; p += (size_t)H*NN*D*2;
    float* gpart= (float*)p; p += (size_t)4*NN*48*4;
    short* comb = (short*)p; p += (size_t)NN*HID*2;
    int*  selix = (int*)p;   p += (size_t)HKV*NN*NSEL*4;

    hipFuncSetAttribute((const void*)k_cattn, hipFuncAttributeMaxDynamicSharedMemorySize, 76032);

    k_prep  <<<5968, 256, 0, stream>>>(q, hidden, combine_w, combiner_w, k, v,
                                        memkv, ksc, vsc,
                                        qbg, hbg, wbg, cwbg, kbg, vTg, ckb, cvtg);
    k_cattn <<<dim3(NN/16, HKV), 256, 76032, stream>>>(qbg, ckb, cvtg, outc, selix);
    k_att3  <<<8832, 256, 0, stream>>>(q, k, v, selix, outf,
                                        qbg, kbg, vTg, outs,
                                        hbg, cwbg, gpart);
    k_comb  <<<NN, 256, 0, stream>>>(outc, outf, outs, gpart, combiner_b, comb);
    k_gemm  <<<dim3(NN/64, HID/64), 256, 0, stream>>>(comb, wbg, out);
}

// Round 6
// 81.563 us; speedup vs baseline: 1.2742x; 1.2742x over previous
//
#include <hip/hip_runtime.h>
#include <hip/hip_bf16.h>
#include <math.h>

#define H    16
#define HKV  4
#define G    4
#define NN   2048
#define D    64
#define HID  1024
#define CB   16
#define W    128
#define NSEL 4
#define WIN  64
#define NEGV -1e10f
#define SCALE 0.125f

typedef __attribute__((ext_vector_type(4))) float f32x4;
typedef __attribute__((ext_vector_type(4))) short short4v;
typedef __attribute__((ext_vector_type(8))) short short8v;

__device__ inline short f2b(float x){
    __hip_bfloat16 h = __float2bfloat16(x);
    return *reinterpret_cast<short*>(&h);
}
__device__ inline float b2f(short s){
    unsigned u = ((unsigned)(unsigned short)s) << 16;
    return __builtin_bit_cast(float, u);
}
#define SWZ(byte, row) ((byte) ^ (((row)&7)<<4))
#define MFMA(a,b,c) __builtin_amdgcn_mfma_f32_16x16x32_bf16(a,b,c,0,0,0)

__device__ inline float wave_sum(float x){ for(int o=32;o;o>>=1) x += __shfl_xor(x,o); return x; }
__device__ inline float wave_max(float x){ for(int o=32;o;o>>=1) x = fmaxf(x,__shfl_xor(x,o)); return x; }

__device__ inline f32x4 vmax4(f32x4 a, f32x4 b){
    f32x4 r; r[0]=fmaxf(a[0],b[0]); r[1]=fmaxf(a[1],b[1]); r[2]=fmaxf(a[2],b[2]); r[3]=fmaxf(a[3],b[3]); return r;
}
__device__ inline f32x4 shflx4(f32x4 x, int o){
    f32x4 r; r[0]=__shfl_xor(x[0],o); r[1]=__shfl_xor(x[1],o); r[2]=__shfl_xor(x[2],o); r[3]=__shfl_xor(x[3],o); return r;
}
__device__ inline f32x4 exp4(f32x4 x){
    f32x4 r; r[0]=expf(x[0]); r[1]=expf(x[1]); r[2]=expf(x[2]); r[3]=expf(x[3]); return r;
}

// ---------------------------------------------------------------------------
// fused prep: converts + V transpose + compressed KV. Block-range dispatch.
__device__ inline void conv_seg(const float* __restrict__ src, short* __restrict__ dst,
                                int b, int t){
    size_t idx = (size_t)b*1024 + t*4;
    f32x4 a = *(const f32x4*)(src + idx);
    short4v r; r[0]=f2b(a[0]); r[1]=f2b(a[1]); r[2]=f2b(a[2]); r[3]=f2b(a[3]);
    *(short4v*)(dst + idx) = r;
}

__global__ __launch_bounds__(256) void k_prep(
    const float* __restrict__ q, const float* __restrict__ hidden,
    const float* __restrict__ combine_w, const float* __restrict__ combiner_w,
    const float* __restrict__ k, const float* __restrict__ v,
    const float* __restrict__ memkv, const float* __restrict__ ksc, const float* __restrict__ vsc,
    short* __restrict__ qb, short* __restrict__ hb, short* __restrict__ wb,
    short* __restrict__ cwb, short* __restrict__ kb16, short* __restrict__ vb16,
    short* __restrict__ vT, short* __restrict__ ckb, short* __restrict__ cvtg)
{
    int b = blockIdx.x, t = threadIdx.x;
    if (b < 2048){ conv_seg(q, qb, b, t); return; }
    b -= 2048;
    if (b < 2048){ conv_seg(hidden, hb, b, t); return; }
    b -= 2048;
    if (b < 1024){ conv_seg(combine_w, wb, b, t); return; }
    b -= 1024;
    if (b < 48){ conv_seg(combiner_w, cwb, b, t); return; }
    b -= 48;
    if (b < 512){ conv_seg(k, kb16, b, t); return; }
    b -= 512;
    if (b < 512){ conv_seg(v, vb16, b, t); return; }
    b -= 512;
    if (b < 128){
        __shared__ float tl[64][65];
        int hk = b>>5, i0 = (b&31)*64;
        for (int u=0;u<4;u++){
            int cid = t + 256*u; int r = cid>>4, ch = cid&15;
            f32x4 a = *(const f32x4*)(v + ((size_t)(hk*NN + i0 + r))*D + ch*4);
            tl[r][ch*4+0]=a[0]; tl[r][ch*4+1]=a[1]; tl[r][ch*4+2]=a[2]; tl[r][ch*4+3]=a[3];
        }
        __syncthreads();
        int d = t>>2, qd = t&3;
        short8v p0, p1;
        #pragma unroll
        for (int e=0;e<8;e++) p0[e] = f2b(tl[qd*16+e][d]);
        #pragma unroll
        for (int e=0;e<8;e++) p1[e] = f2b(tl[qd*16+8+e][d]);
        short* dst = vT + ((size_t)(hk*64 + d))*NN + i0 + qd*16;
        *(short8v*)dst = p0;
        *(short8v*)(dst+8) = p1;
        return;
    }
    b -= 128;
    {
        int j = b;
        int hk = t>>6, d = t&63;
        if (j > 128){
            if (j < 144) ckb[((size_t)(hk*144 + j))*64 + d] = 0;
            cvtg[((size_t)(hk*64 + d))*160 + j] = 0;
            return;
        }
        float xk, xv;
        if (j==0){ xk = memkv[(0*HKV+hk)*D + d]; xv = memkv[(HKV+hk)*D + d]; }
        else {
            int jb = j-1;
            const float* kp = k + ((size_t)(hk*NN + jb*CB))*D + d;
            const float* vp = v + ((size_t)(hk*NN + jb*CB))*D + d;
            float sk=0.f, sv=0.f;
            #pragma unroll
            for (int tt=0;tt<CB;tt++){ sk += kp[tt*D]; sv += vp[tt*D]; }
            xk = sk*(1.0f/CB); xv = sv*(1.0f/CB);
            float msk = wave_sum(xk*xk)*(1.0f/D);
            float msv = wave_sum(xv*xv)*(1.0f/D);
            xk = xk*rsqrtf(msk+1e-6f)*ksc[d];
            xv = xv*rsqrtf(msv+1e-6f)*vsc[d];
        }
        ckb[((size_t)(hk*144 + j))*64 + d] = f2b(xk);
        cvtg[((size_t)(hk*64 + d))*160 + j] = f2b(xv);
    }
}

// ---------------------------------------------------------------------------
// compressed attention + importance + top-k. Block = (hk, 16 tokens), 4 waves.
__global__ __launch_bounds__(256) void k_cattn(
    const short* __restrict__ qb, const short* __restrict__ ckb, const short* __restrict__ cvt_g,
    short* __restrict__ outc, int* __restrict__ selidx)
{
    extern __shared__ char smem[];
    char* aq  = smem;                      // 64 * 128 = 8192
    char* ckl = smem + 8192;               // 144 * 128 = 18432
    char* cvl = smem + 26624;              // 64 * 320 = 20480
    char* pl  = smem + 47104;              // 64 * 320 = 20480
    float* impl = (float*)(smem + 67584);  // 16*128 f32
    float* psl  = (float*)(smem + 75776);  // 64 f32
    int i0 = blockIdx.x*16, hk = blockIdx.y, t = threadIdx.x;

    for (int u=0;u<2;u++){
        int cid = t + 256*u; int row = cid>>3, ch = cid&7;
        const short* src = qb + ((size_t)((hk*G + (row&3))*NN + i0 + (row>>2)))*D + ch*8;
        *(short8v*)(aq + SWZ(row*128 + ch*16, row)) = *(const short8v*)src;
    }
    for (int u=0;u<5;u++){
        int cid = t + 256*u;
        if (cid < 1152){
            int row = cid>>3, ch = cid&7;
            const short* src = ckb + ((size_t)(hk*144 + row))*64 + ch*8;
            *(short8v*)(ckl + SWZ(row*128 + ch*16, row)) = *(const short8v*)src;
        }
    }
    for (int u=0;u<5;u++){
        int cid = t + 256*u;
        int row = cid/20, ch = cid%20;
        *(short8v*)(cvl + SWZ(row*320 + ch*16, row)) =
            *(const short8v*)(cvt_g + ((size_t)(hk*64 + row))*160 + ch*8);
    }
    if (t < 128){
        int row = t>>1, sl = t&1;
        *(short8v*)(pl + SWZ(row*320 + 288 + sl*16, row)) = (short8v)0;
    }
    __syncthreads();

    int w = t>>6, lane = t&63, c = lane&15, lg = lane>>4;
    f32x4 acc[9];
    #pragma unroll
    for (int ct=0;ct<9;ct++) acc[ct] = (f32x4)0.f;

    #pragma unroll
    for (int ks=0;ks<2;ks++){
        int arow = w*16 + c;
        short8v af = *(short8v*)(aq + SWZ(arow*128 + ks*64 + lg*16, arow));
        #pragma unroll
        for (int ct=0;ct<9;ct++){
            int row = ct*16 + c;
            short8v bf = *(short8v*)(ckl + SWZ(row*128 + ks*64 + lg*16, row));
            acc[ct] = MFMA(af, bf, acc[ct]);
        }
    }

    {
        int tloc = w*4 + lg;
        int ii = i0 + tloc;
        #pragma unroll
        for (int ct=0;ct<9;ct++){
            int j = ct*16 + c;
            bool vis = (j==0) || (j<=128 && j*16 <= ii);
            f32x4 s = acc[ct]*SCALE;
            if (!vis){ s[0]=NEGV; s[1]=NEGV; s[2]=NEGV; s[3]=NEGV; }
            acc[ct] = s;
        }
        #pragma unroll
        for (int ct=0;ct<9;ct++){
            int j = ct*16 + c;
            if (j>=1 && j<=128){
                f32x4 s = acc[ct];
                impl[tloc*128 + (j-1)] = 0.25f*(s[0]+s[1]+s[2]+s[3]);
            }
        }
        f32x4 mx = acc[0];
        #pragma unroll
        for (int ct=1;ct<9;ct++) mx = vmax4(mx, acc[ct]);
        #pragma unroll
        for (int o=1;o<16;o<<=1) mx = vmax4(mx, shflx4(mx,o));
        f32x4 sum = (f32x4)0.f;
        #pragma unroll
        for (int ct=0;ct<9;ct++){ acc[ct] = exp4(acc[ct]-mx); sum += acc[ct]; }
        #pragma unroll
        for (int o=1;o<16;o<<=1) sum += shflx4(sum,o);
        #pragma unroll
        for (int ct=0;ct<9;ct++){
            #pragma unroll
            for (int reg=0;reg<4;reg++){
                int row = w*16 + lg*4 + reg;
                *(short*)(pl + SWZ(row*320 + (ct*16+c)*2, row)) = f2b(acc[ct][reg]);
            }
        }
        if (c==0){
            #pragma unroll
            for (int reg=0;reg<4;reg++) psl[w*16 + lg*4 + reg] = sum[reg];
        }
    }
    __syncthreads();

    #pragma unroll 1
    for (int s4=0;s4<4;s4++){
        int tt = w*4 + s4;
        float v0 = impl[tt*128 + lane];
        float v1 = impl[tt*128 + 64 + lane];
        int sel[4];
        #pragma unroll
        for (int r4=0;r4<4;r4++){
            float bv; int bj;
            if (v1 > v0){ bv=v1; bj=lane+64; } else { bv=v0; bj=lane; }
            #pragma unroll
            for (int o=32;o;o>>=1){
                float ov = __shfl_xor(bv,o);
                int oj = __shfl_xor(bj,o);
                if (ov > bv || (ov==bv && oj<bj)){ bv=ov; bj=oj; }
            }
            sel[r4]=bj;
            if (bj==lane) v0 = -INFINITY;
            else if (bj==lane+64) v1 = -INFINITY;
        }
        if (lane==0){
            int* sp = selidx + ((size_t)(hk*NN + i0 + tt))*NSEL;
            sp[0]=sel[0]; sp[1]=sel[1]; sp[2]=sel[2]; sp[3]=sel[3];
        }
    }

    f32x4 pv[4];
    #pragma unroll
    for (int ctd=0;ctd<4;ctd++) pv[ctd] = (f32x4)0.f;
    #pragma unroll
    for (int ks=0;ks<5;ks++){
        int arow = w*16 + c;
        short8v pf = *(short8v*)(pl + SWZ(arow*320 + ks*64 + lg*16, arow));
        #pragma unroll
        for (int ctd=0;ctd<4;ctd++){
            int row = ctd*16 + c;
            short8v bf = *(short8v*)(cvl + SWZ(row*320 + ks*64 + lg*16, row));
            pv[ctd] = MFMA(pf, bf, pv[ctd]);
        }
    }
    #pragma unroll
    for (int ctd=0;ctd<4;ctd++)
        #pragma unroll
        for (int reg=0;reg<4;reg++){
            int row = w*16 + lg*4 + reg;
            float inv = 1.0f/psl[row];
            int hh = hk*G + reg;
            int ii = i0 + (row>>2);
            outc[((size_t)(hh*NN + ii))*D + ctd*16 + c] = f2b(pv[ctd][reg]*inv);
        }
}

// ---------------------------------------------------------------------------
// selected-block attention, bf16 staging, lean LDS (17.4 KB). Block = (i, hk).
__global__ __launch_bounds__(256) void k_sel(
    const short* __restrict__ qb, const short* __restrict__ kbg, const short* __restrict__ vbg,
    const int* __restrict__ selidx, short* __restrict__ outf)
{
    __shared__ char ksl[64*128];
    __shared__ char vsl[64*128];
    __shared__ float ps[256];
    __shared__ int sel_s[4];
    int i = blockIdx.x, hk = blockIdx.y, t = threadIdx.x;
    if (t < 4) sel_s[t] = selidx[((size_t)(hk*NN + i))*NSEL + t];
    __syncthreads();
    for (int u=0;u<2;u++){
        int cid = t + 256*u; int row = cid>>3, ch = cid&7;
        int pos = sel_s[row>>4]*CB + (row&15);
        *(short8v*)(ksl + SWZ(row*128 + ch*16, row)) =
            *(const short8v*)(kbg + ((size_t)(hk*NN + pos))*D + ch*8);
        *(short8v*)(vsl + row*128 + ch*16) =
            *(const short8v*)(vbg + ((size_t)(hk*NN + pos))*D + ch*8);
    }
    int wv = t>>6, lane = t&63;
    // q in regs (bf16), wave-uniform broadcast loads
    short8v qv[8];
    {
        const short* qrow = qb + ((size_t)((hk*G + wv)*NN + i))*D;
        #pragma unroll
        for (int ch=0;ch<8;ch++) qv[ch] = *(const short8v*)(qrow + ch*8);
    }
    __syncthreads();
    int pos_l = sel_s[lane>>4]*CB + (lane&15);
    float s = 0.f;
    #pragma unroll
    for (int ch=0;ch<8;ch++){
        short8v kk = *(short8v*)(ksl + SWZ(lane*128 + ch*16, lane));
        #pragma unroll
        for (int e=0;e<8;e++) s += b2f(qv[ch][e]) * b2f(kk[e]);
    }
    s *= SCALE;
    if (pos_l > i) s = NEGV;
    float m = wave_max(s);
    float p = expf(s - m);
    float psum = wave_sum(p);
    ps[wv*64 + lane] = p;
    __syncthreads();
    int jg = lane>>4, dg = lane&15;
    float inv = 1.0f/psum;
    f32x4 partial = (f32x4)0.f;
    #pragma unroll
    for (int jj=0;jj<16;jj++){
        int j = jg*16 + jj;
        float pw = ps[wv*64 + j];
        short4v vv = *(short4v*)(vsl + j*128 + dg*8);
        partial[0] += pw*b2f(vv[0]); partial[1] += pw*b2f(vv[1]);
        partial[2] += pw*b2f(vv[2]); partial[3] += pw*b2f(vv[3]);
    }
    partial += shflx4(partial, 16);
    partial += shflx4(partial, 32);
    if (lane < 16){
        short4v r;
        r[0]=f2b(partial[0]*inv); r[1]=f2b(partial[1]*inv);
        r[2]=f2b(partial[2]*inv); r[3]=f2b(partial[3]*inv);
        *(short4v*)(outf + ((size_t)((hk*G+wv)*NN + i))*D + dg*4) = r;
    }
}

// ---------------------------------------------------------------------------
// fused: swin (blocks 0..511) + gates (512..639). LDS 41216 B (P aliases K tile).
__global__ __launch_bounds__(256) void k_swg(
    const short* __restrict__ qb, const short* __restrict__ kb16, const short* __restrict__ vT,
    short* __restrict__ outs,
    const short* __restrict__ hb, const short* __restrict__ cwb, float* __restrict__ gpart)
{
    __shared__ char smem[41216];
    int b = blockIdx.x, t = threadIdx.x;

    if (b < 512){
        char* aq = smem;                     // 8192
        char* kb = smem + 8192;              // 16384 (pl aliases after QK^T)
        char* vl = smem + 24576;             // 16384
        float* psl = (float*)(smem + 40960); // 256
        char* pl = kb;
        int i0 = (b & 31)*64, h = b >> 5;
        int hk = h >> 2;
        int pa = i0 - 64;
        for (int u=0;u<2;u++){
            int cid = t + 256*u; int row = cid>>3, ch = cid&7;
            *(short8v*)(aq + SWZ(row*128 + ch*16, row)) =
                *(const short8v*)(qb + ((size_t)(h*NN + i0 + row))*D + ch*8);
        }
        for (int u=0;u<4;u++){
            int cid = t + 256*u; int row = cid>>3, ch = cid&7;
            int pos = pa + row; pos = pos < 0 ? 0 : pos;
            *(short8v*)(kb + SWZ(row*128 + ch*16, row)) =
                *(const short8v*)(kb16 + ((size_t)(hk*NN + pos))*D + ch*8);
        }
        for (int u=0;u<4;u++){
            int cid = t + 256*u; int d = cid>>4, ch = cid&15;
            int ps0 = pa + ch*8;
            short8v val;
            const short* src = vT + ((size_t)(hk*64 + d))*NN + ps0;
            if (ps0 >= 0) val = *(const short8v*)src;
            else {
                #pragma unroll
                for (int e=0;e<8;e++){ int pp = ps0+e; pp = pp<0?0:pp; val[e] = vT[((size_t)(hk*64+d))*NN + pp]; }
            }
            *(short8v*)(vl + SWZ(d*256 + ch*16, d)) = val;
        }
        __syncthreads();
        int w = t>>6, lane = t&63, c = lane&15, lg = lane>>4;
        f32x4 acc[8];
        #pragma unroll
        for (int ct=0;ct<8;ct++) acc[ct] = (f32x4)0.f;
        #pragma unroll
        for (int ks=0;ks<2;ks++){
            int arow = w*16 + c;
            short8v af = *(short8v*)(aq + SWZ(arow*128 + ks*64 + lg*16, arow));
            #pragma unroll
            for (int ct=0;ct<8;ct++){
                int brow = ct*16 + c;
                short8v bf = *(short8v*)(kb + SWZ(brow*128 + ks*64 + lg*16, brow));
                acc[ct] = MFMA(af, bf, acc[ct]);
            }
        }
        #pragma unroll
        for (int ct=0;ct<8;ct++){
            int j = ct*16 + c;
            #pragma unroll
            for (int reg=0;reg<4;reg++){
                int tl = w*16 + lg*4 + reg;
                bool vis = (j >= tl+1) && (j <= tl+64) && (pa + j >= 0);
                float s = acc[ct][reg]*SCALE;
                acc[ct][reg] = vis ? s : NEGV;
            }
        }
        f32x4 mx = acc[0];
        #pragma unroll
        for (int ct=1;ct<8;ct++) mx = vmax4(mx, acc[ct]);
        #pragma unroll
        for (int o=1;o<16;o<<=1) mx = vmax4(mx, shflx4(mx,o));
        f32x4 sum = (f32x4)0.f;
        #pragma unroll
        for (int ct=0;ct<8;ct++){ acc[ct] = exp4(acc[ct]-mx); sum += acc[ct]; }
        #pragma unroll
        for (int o=1;o<16;o<<=1) sum += shflx4(sum,o);
        __syncthreads();   // all waves done reading kb before P overwrites it
        #pragma unroll
        for (int ct=0;ct<8;ct++){
            #pragma unroll
            for (int reg=0;reg<4;reg++){
                int row = w*16 + lg*4 + reg;
                *(short*)(pl + SWZ(row*256 + (ct*16+c)*2, row)) = f2b(acc[ct][reg]);
            }
        }
        if (c==0){
            #pragma unroll
            for (int reg=0;reg<4;reg++) psl[w*16+lg*4+reg] = sum[reg];
        }
        __syncthreads();
        f32x4 pv[4];
        #pragma unroll
        for (int ctd=0;ctd<4;ctd++) pv[ctd] = (f32x4)0.f;
        #pragma unroll
        for (int ks=0;ks<4;ks++){
            int arow = w*16 + c;
            short8v pf = *(short8v*)(pl + SWZ(arow*256 + ks*64 + lg*16, arow));
            #pragma unroll
            for (int ctd=0;ctd<4;ctd++){
                int brow = ctd*16 + c;
                short8v bf = *(short8v*)(vl + SWZ(brow*256 + ks*64 + lg*16, brow));
                pv[ctd] = MFMA(pf, bf, pv[ctd]);
            }
        }
        #pragma unroll
        for (int ctd=0;ctd<4;ctd++)
            #pragma unroll
            for (int reg=0;reg<4;reg++){
                int row = w*16 + lg*4 + reg;
                float inv = 1.0f/psl[row];
                outs[((size_t)(h*NN + i0 + row))*D + ctd*16 + c] = f2b(pv[ctd][reg]*inv);
            }
        return;
    }
    {
        // gates split-K partial GEMM
        int idx = b - 512;
        char* ha = smem;                  // 8192
        char* bl = smem + 8192;           // 6144
        int i0 = (idx & 31)*64, ky = idx >> 5;
        int w = t>>6, lane = t&63, c = lane&15, lg = lane>>4;
        f32x4 acc[3];
        #pragma unroll
        for (int ct=0;ct<3;ct++) acc[ct] = (f32x4)0.f;
        for (int kc=0;kc<4;kc++){
            int kbase = ky*256 + kc*64;
            if (kc) __syncthreads();
            for (int u=0;u<2;u++){
                int cid = t + 256*u; int row = cid>>3, ch = cid&7;
                *(short8v*)(ha + SWZ(row*128 + ch*16, row)) =
                    *(const short8v*)(hb + (size_t)(i0+row)*HID + kbase + ch*8);
            }
            for (int u=0;u<2;u++){
                int cid = t + 256*u;
                if (cid < 384){
                    int row = cid>>3, ch = cid&7;
                    *(short8v*)(bl + SWZ(row*128 + ch*16, row)) =
                        *(const short8v*)(cwb + (size_t)row*HID + kbase + ch*8);
                }
            }
            __syncthreads();
            #pragma unroll
            for (int ks=0;ks<2;ks++){
                int arow = w*16 + c;
                short8v af = *(short8v*)(ha + SWZ(arow*128 + ks*64 + lg*16, arow));
                #pragma unroll
                for (int ct=0;ct<3;ct++){
                    int brow = ct*16 + c;
                    short8v bf = *(short8v*)(bl + SWZ(brow*128 + ks*64 + lg*16, brow));
                    acc[ct] = MFMA(af, bf, acc[ct]);
                }
            }
        }
        #pragma unroll
        for (int ct=0;ct<3;ct++)
            #pragma unroll
            for (int reg=0;reg<4;reg++){
                int row = w*16 + lg*4 + reg;
                gpart[((size_t)ky*NN + i0 + row)*48 + ct*16 + c] = acc[ct][reg];
            }
    }
}

// ---------------------------------------------------------------------------
// gated combine -> comb bf16 [N][HID]
__global__ __launch_bounds__(256) void k_comb(
    const short* __restrict__ outc, const short* __restrict__ outf, const short* __restrict__ outs_,
    const float* __restrict__ gpart, const float* __restrict__ cb, short* __restrict__ comb)
{
    __shared__ float gs[48];
    int i = blockIdx.x, t = threadIdx.x;
    if (t < 48){
        float s = gpart[(size_t)0*NN*48 + i*48 + t] + gpart[(size_t)1*NN*48 + i*48 + t]
                + gpart[(size_t)2*NN*48 + i*48 + t] + gpart[(size_t)3*NN*48 + i*48 + t] + cb[t];
        gs[t] = 1.0f/(1.0f+expf(-s));
    }
    __syncthreads();
    int hh = t>>4, d0 = (t&15)*4;
    float g0 = gs[hh*3], g1 = gs[hh*3+1], g2 = gs[hh*3+2];
    size_t off = ((size_t)(hh*NN + i))*D + d0;
    short4v a = *(const short4v*)(outc + off);
    short4v b = *(const short4v*)(outf + off);
    short4v cc = *(const short4v*)(outs_ + off);
    short4v r;
    #pragma unroll
    for (int e=0;e<4;e++) r[e] = f2b(g0*b2f(a[e]) + g1*b2f(b[e]) + g2*b2f(cc[e]));
    *(short4v*)(comb + (size_t)i*HID + t*4) = r;
}

// ---------------------------------------------------------------------------
// out = comb (bf16 2048x1024) @ wb^T (bf16 1024x1024), f32 out. 64x64 tile, dbuf.
__global__ __launch_bounds__(256) void k_gemm(
    const short* __restrict__ A, const short* __restrict__ Bw, float* __restrict__ out)
{
    __shared__ char ab[2][64*128];
    __shared__ char bb[2][64*128];
    int m0 = blockIdx.x*64, n0 = blockIdx.y*64, t = threadIdx.x;
    int w = t>>6, lane = t&63, c = lane&15, lg = lane>>4;
    int r0 = t>>3, ch0 = t&7;
    f32x4 acc[4];
    #pragma unroll
    for (int ct=0;ct<4;ct++) acc[ct] = (f32x4)0.f;
    const short* Ap = A  + (size_t)(m0+r0)*HID + ch0*8;
    const short* Bp = Bw + (size_t)(n0+r0)*HID + ch0*8;
    short8v ra0 = *(const short8v*)(Ap);
    short8v ra1 = *(const short8v*)(Ap + 32*HID);
    short8v rb0 = *(const short8v*)(Bp);
    short8v rb1 = *(const short8v*)(Bp + 32*HID);
    for (int kc=0;kc<16;kc++){
        char* abuf = ab[kc&1];
        char* bbuf = bb[kc&1];
        *(short8v*)(abuf + SWZ(r0*128 + ch0*16, r0)) = ra0;
        *(short8v*)(abuf + SWZ((r0+32)*128 + ch0*16, r0+32)) = ra1;
        *(short8v*)(bbuf + SWZ(r0*128 + ch0*16, r0)) = rb0;
        *(short8v*)(bbuf + SWZ((r0+32)*128 + ch0*16, r0+32)) = rb1;
        __syncthreads();
        if (kc < 15){
            const short* Ap2 = Ap + (kc+1)*64;
            const short* Bp2 = Bp + (kc+1)*64;
            ra0 = *(const short8v*)(Ap2);
            ra1 = *(const short8v*)(Ap2 + 32*HID);
            rb0 = *(const short8v*)(Bp2);
            rb1 = *(const short8v*)(Bp2 + 32*HID);
        }
        #pragma unroll
        for (int ks=0;ks<2;ks++){
            int arow = w*16 + c;
            short8v af = *(short8v*)(abuf + SWZ(arow*128 + ks*64 + lg*16, arow));
            #pragma unroll
            for (int ct=0;ct<4;ct++){
                int brow = ct*16 + c;
                short8v bf = *(short8v*)(bbuf + SWZ(brow*128 + ks*64 + lg*16, brow));
                acc[ct] = MFMA(af, bf, acc[ct]);
            }
        }
    }
    #pragma unroll
    for (int ct=0;ct<4;ct++)
        #pragma unroll
        for (int reg=0;reg<4;reg++){
            int row = w*16 + lg*4 + reg;
            out[((size_t)(m0+row))*HID + n0 + ct*16 + c] = acc[ct][reg];
        }
}

// ---------------------------------------------------------------------------
extern "C" void kernel_launch(void* const* d_in, const int* in_sizes, int n_in,
                              void* d_out, int out_size, void* d_ws, size_t ws_size,
                              hipStream_t stream)
{
    const float* hidden     = (const float*)d_in[0];
    const float* q          = (const float*)d_in[1];
    const float* k          = (const float*)d_in[2];
    const float* v          = (const float*)d_in[3];
    const float* memkv      = (const float*)d_in[4];
    const float* ksc        = (const float*)d_in[5];
    const float* vsc        = (const float*)d_in[6];
    const float* combiner_w = (const float*)d_in[7];
    const float* combiner_b = (const float*)d_in[8];
    const float* combine_w  = (const float*)d_in[9];
    float* out = (float*)d_out;

    char* p = (char*)d_ws;
    short* ckb  = (short*)p; p += (size_t)HKV*144*64*2;
    short* cvtg = (short*)p; p += (size_t)HKV*64*160*2;
    short* qbg  = (short*)p; p += (size_t)H*NN*D*2;
    short* hbg  = (short*)p; p += (size_t)NN*HID*2;
    short* wbg  = (short*)p; p += (size_t)HID*HID*2;
    short* cwbg = (short*)p; p += (size_t)48*HID*2;
    short* kbg  = (short*)p; p += (size_t)HKV*NN*D*2;
    short* vbg  = (short*)p; p += (size_t)HKV*NN*D*2;
    short* vTg  = (short*)p; p += (size_t)HKV*64*NN*2;
    short* outc = (short*)p; p += (size_t)H*NN*D*2;
    short* outf = (short*)p; p += (size_t)H*NN*D*2;
    short* outs = (short*)p; p += (size_t)H*NN*D*2;
    float* gpart= (float*)p; p += (size_t)4*NN*48*4;
    short* comb = (short*)p; p += (size_t)NN*HID*2;
    int*  selix = (int*)p;   p += (size_t)HKV*NN*NSEL*4;

    hipFuncSetAttribute((const void*)k_cattn, hipFuncAttributeMaxDynamicSharedMemorySize, 76032);

    k_prep  <<<6480, 256, 0, stream>>>(q, hidden, combine_w, combiner_w, k, v,
                                        memkv, ksc, vsc,
                                        qbg, hbg, wbg, cwbg, kbg, vbg, vTg, ckb, cvtg);
    k_cattn <<<dim3(NN/16, HKV), 256, 76032, stream>>>(qbg, ckb, cvtg, outc, selix);
    k_swg   <<<640, 256, 0, stream>>>(qbg, kbg, vTg, outs, hbg, cwbg, gpart);
    k_sel   <<<dim3(NN, HKV), 256, 0, stream>>>(qbg, kbg, vbg, selix, outf);
    k_comb  <<<NN, 256, 0, stream>>>(outc, outf, outs, gpart, combiner_b, comb);
    k_gemm  <<<dim3(NN/64, HID/64), 256, 0, stream>>>(comb, wbg, out);
}

// Round 7
// 81.043 us; speedup vs baseline: 1.2824x; 1.0064x over previous
//
#include <hip/hip_runtime.h>
#include <hip/hip_bf16.h>
#include <math.h>

#define H    16
#define HKV  4
#define G    4
#define NN   2048
#define D    64
#define HID  1024
#define CB   16
#define W    128
#define NSEL 4
#define WIN  64
#define NEGV -1e10f
#define SCALE 0.125f

typedef __attribute__((ext_vector_type(4))) float f32x4;
typedef __attribute__((ext_vector_type(4))) short short4v;
typedef __attribute__((ext_vector_type(8))) short short8v;

__device__ inline short f2b(float x){
    __hip_bfloat16 h = __float2bfloat16(x);
    return *reinterpret_cast<short*>(&h);
}
__device__ inline float b2f(short s){
    unsigned u = ((unsigned)(unsigned short)s) << 16;
    return __builtin_bit_cast(float, u);
}
#define SWZ(byte, row) ((byte) ^ (((row)&7)<<4))
#define MFMA(a,b,c) __builtin_amdgcn_mfma_f32_16x16x32_bf16(a,b,c,0,0,0)

__device__ inline float wave_sum(float x){ for(int o=32;o;o>>=1) x += __shfl_xor(x,o); return x; }
__device__ inline float wave_max(float x){ for(int o=32;o;o>>=1) x = fmaxf(x,__shfl_xor(x,o)); return x; }

__device__ inline f32x4 vmax4(f32x4 a, f32x4 b){
    f32x4 r; r[0]=fmaxf(a[0],b[0]); r[1]=fmaxf(a[1],b[1]); r[2]=fmaxf(a[2],b[2]); r[3]=fmaxf(a[3],b[3]); return r;
}
__device__ inline f32x4 shflx4(f32x4 x, int o){
    f32x4 r; r[0]=__shfl_xor(x[0],o); r[1]=__shfl_xor(x[1],o); r[2]=__shfl_xor(x[2],o); r[3]=__shfl_xor(x[3],o); return r;
}
__device__ inline f32x4 exp4(f32x4 x){
    f32x4 r; r[0]=expf(x[0]); r[1]=expf(x[1]); r[2]=expf(x[2]); r[3]=expf(x[3]); return r;
}

// ---------------------------------------------------------------------------
// fused prep: converts + V transpose (also emits bf16 V) + compressed KV.
__device__ inline void conv_seg(const float* __restrict__ src, short* __restrict__ dst,
                                int b, int t){
    size_t idx = (size_t)b*1024 + t*4;
    f32x4 a = *(const f32x4*)(src + idx);
    short4v r; r[0]=f2b(a[0]); r[1]=f2b(a[1]); r[2]=f2b(a[2]); r[3]=f2b(a[3]);
    *(short4v*)(dst + idx) = r;
}

__global__ __launch_bounds__(256) void k_prep(
    const float* __restrict__ q, const float* __restrict__ hidden,
    const float* __restrict__ combine_w, const float* __restrict__ combiner_w,
    const float* __restrict__ k, const float* __restrict__ v,
    const float* __restrict__ memkv, const float* __restrict__ ksc, const float* __restrict__ vsc,
    short* __restrict__ qb, short* __restrict__ hb, short* __restrict__ wb,
    short* __restrict__ cwb, short* __restrict__ kb16, short* __restrict__ vb16,
    short* __restrict__ vT, short* __restrict__ ckb, short* __restrict__ cvtg)
{
    int b = blockIdx.x, t = threadIdx.x;
    if (b < 2048){ conv_seg(q, qb, b, t); return; }
    b -= 2048;
    if (b < 2048){ conv_seg(hidden, hb, b, t); return; }
    b -= 2048;
    if (b < 1024){ conv_seg(combine_w, wb, b, t); return; }
    b -= 1024;
    if (b < 48){ conv_seg(combiner_w, cwb, b, t); return; }
    b -= 48;
    if (b < 512){ conv_seg(k, kb16, b, t); return; }
    b -= 512;
    if (b < 128){
        // V transpose (emit vT) + bf16 V (emit vb16)
        __shared__ float tl[64][65];
        int hk = b>>5, i0 = (b&31)*64;
        for (int u=0;u<4;u++){
            int cid = t + 256*u; int r = cid>>4, ch = cid&15;
            size_t off = ((size_t)(hk*NN + i0 + r))*D + ch*4;
            f32x4 a = *(const f32x4*)(v + off);
            tl[r][ch*4+0]=a[0]; tl[r][ch*4+1]=a[1]; tl[r][ch*4+2]=a[2]; tl[r][ch*4+3]=a[3];
            short4v rb; rb[0]=f2b(a[0]); rb[1]=f2b(a[1]); rb[2]=f2b(a[2]); rb[3]=f2b(a[3]);
            *(short4v*)(vb16 + off) = rb;
        }
        __syncthreads();
        int d = t>>2, qd = t&3;
        short8v p0, p1;
        #pragma unroll
        for (int e=0;e<8;e++) p0[e] = f2b(tl[qd*16+e][d]);
        #pragma unroll
        for (int e=0;e<8;e++) p1[e] = f2b(tl[qd*16+8+e][d]);
        short* dst = vT + ((size_t)(hk*64 + d))*NN + i0 + qd*16;
        *(short8v*)dst = p0;
        *(short8v*)(dst+8) = p1;
        return;
    }
    b -= 128;
    {
        int j = b;
        int hk = t>>6, d = t&63;
        if (j > 128){
            if (j < 144) ckb[((size_t)(hk*144 + j))*64 + d] = 0;
            cvtg[((size_t)(hk*64 + d))*160 + j] = 0;
            return;
        }
        float xk, xv;
        if (j==0){ xk = memkv[(0*HKV+hk)*D + d]; xv = memkv[(HKV+hk)*D + d]; }
        else {
            int jb = j-1;
            const float* kp = k + ((size_t)(hk*NN + jb*CB))*D + d;
            const float* vp = v + ((size_t)(hk*NN + jb*CB))*D + d;
            float sk=0.f, sv=0.f;
            #pragma unroll
            for (int tt=0;tt<CB;tt++){ sk += kp[tt*D]; sv += vp[tt*D]; }
            xk = sk*(1.0f/CB); xv = sv*(1.0f/CB);
            float msk = wave_sum(xk*xk)*(1.0f/D);
            float msv = wave_sum(xv*xv)*(1.0f/D);
            xk = xk*rsqrtf(msk+1e-6f)*ksc[d];
            xv = xv*rsqrtf(msv+1e-6f)*vsc[d];
        }
        ckb[((size_t)(hk*144 + j))*64 + d] = f2b(xk);
        cvtg[((size_t)(hk*64 + d))*160 + j] = f2b(xv);
    }
}

// ---------------------------------------------------------------------------
// compressed attention + importance + top-k. Block = (hk, 16 tokens), 4 waves.
// LDS diet: 35072 B static (P aliases aq/ckl; CV^T read direct from L1/L2).
__global__ __launch_bounds__(256) void k_cattn(
    const short* __restrict__ qb, const short* __restrict__ ckb, const short* __restrict__ cvt_g,
    short* __restrict__ outc, int* __restrict__ selidx)
{
    __shared__ char smem[35072];
    char* aq  = smem;                      // 64*128 = 8192
    char* ckl = smem + 8192;               // 144*128 = 18432 (ends 26624)
    char* pl  = smem;                      // alias: 64*320 = 20480 <= 26624
    float* impl = (float*)(smem + 26624);  // 16*128 f32 = 8192 (ends 34816)
    float* psl  = (float*)(smem + 34816);  // 64 f32 = 256
    int i0 = blockIdx.x*16, hk = blockIdx.y, t = threadIdx.x;
    const short* cvhk = cvt_g + (size_t)hk*64*160;

    for (int u=0;u<2;u++){
        int cid = t + 256*u; int row = cid>>3, ch = cid&7;
        const short* src = qb + ((size_t)((hk*G + (row&3))*NN + i0 + (row>>2)))*D + ch*8;
        *(short8v*)(aq + SWZ(row*128 + ch*16, row)) = *(const short8v*)src;
    }
    for (int u=0;u<5;u++){
        int cid = t + 256*u;
        if (cid < 1152){
            int row = cid>>3, ch = cid&7;
            const short* src = ckb + ((size_t)(hk*144 + row))*64 + ch*8;
            *(short8v*)(ckl + SWZ(row*128 + ch*16, row)) = *(const short8v*)src;
        }
    }
    __syncthreads();

    int w = t>>6, lane = t&63, c = lane&15, lg = lane>>4;
    f32x4 acc[9];
    #pragma unroll
    for (int ct=0;ct<9;ct++) acc[ct] = (f32x4)0.f;

    #pragma unroll
    for (int ks=0;ks<2;ks++){
        int arow = w*16 + c;
        short8v af = *(short8v*)(aq + SWZ(arow*128 + ks*64 + lg*16, arow));
        #pragma unroll
        for (int ct=0;ct<9;ct++){
            int row = ct*16 + c;
            short8v bf = *(short8v*)(ckl + SWZ(row*128 + ks*64 + lg*16, row));
            acc[ct] = MFMA(af, bf, acc[ct]);
        }
    }

    // scale + mask + importance(LDS) + softmax (regs)
    f32x4 sum;
    {
        int tloc = w*4 + lg;
        int ii = i0 + tloc;
        #pragma unroll
        for (int ct=0;ct<9;ct++){
            int j = ct*16 + c;
            bool vis = (j==0) || (j<=128 && j*16 <= ii);
            f32x4 s = acc[ct]*SCALE;
            if (!vis){ s[0]=NEGV; s[1]=NEGV; s[2]=NEGV; s[3]=NEGV; }
            acc[ct] = s;
        }
        #pragma unroll
        for (int ct=0;ct<9;ct++){
            int j = ct*16 + c;
            if (j>=1 && j<=128){
                f32x4 s = acc[ct];
                impl[tloc*128 + (j-1)] = 0.25f*(s[0]+s[1]+s[2]+s[3]);
            }
        }
        f32x4 mx = acc[0];
        #pragma unroll
        for (int ct=1;ct<9;ct++) mx = vmax4(mx, acc[ct]);
        #pragma unroll
        for (int o=1;o<16;o<<=1) mx = vmax4(mx, shflx4(mx,o));
        sum = (f32x4)0.f;
        #pragma unroll
        for (int ct=0;ct<9;ct++){ acc[ct] = exp4(acc[ct]-mx); sum += acc[ct]; }
        #pragma unroll
        for (int o=1;o<16;o<<=1) sum += shflx4(sum,o);
    }
    __syncthreads();   // QK reads of aq/ckl done in all waves; impl visible

    // write P into aliased region + pad zeros + psl
    #pragma unroll
    for (int ct=0;ct<9;ct++){
        #pragma unroll
        for (int reg=0;reg<4;reg++){
            int row = w*16 + lg*4 + reg;
            *(short*)(pl + SWZ(row*320 + (ct*16+c)*2, row)) = f2b(acc[ct][reg]);
        }
    }
    #pragma unroll
    for (int reg=0;reg<4;reg++){
        int row = w*16 + lg*4 + reg;
        *(short*)(pl + SWZ(row*320 + (144+c)*2, row)) = 0;
    }
    if (c==0){
        #pragma unroll
        for (int reg=0;reg<4;reg++) psl[w*16 + lg*4 + reg] = sum[reg];
    }
    __syncthreads();

    // top-k: 4 tokens per wave (reads impl)
    #pragma unroll 1
    for (int s4=0;s4<4;s4++){
        int tt = w*4 + s4;
        float v0 = impl[tt*128 + lane];
        float v1 = impl[tt*128 + 64 + lane];
        int sel[4];
        #pragma unroll
        for (int r4=0;r4<4;r4++){
            float bv; int bj;
            if (v1 > v0){ bv=v1; bj=lane+64; } else { bv=v0; bj=lane; }
            #pragma unroll
            for (int o=32;o;o>>=1){
                float ov = __shfl_xor(bv,o);
                int oj = __shfl_xor(bj,o);
                if (ov > bv || (ov==bv && oj<bj)){ bv=ov; bj=oj; }
            }
            sel[r4]=bj;
            if (bj==lane) v0 = -INFINITY;
            else if (bj==lane+64) v1 = -INFINITY;
        }
        if (lane==0){
            int* sp = selidx + ((size_t)(hk*NN + i0 + tt))*NSEL;
            sp[0]=sel[0]; sp[1]=sel[1]; sp[2]=sel[2]; sp[3]=sel[3];
        }
    }

    // PV: P from LDS, CV^T direct from global (L1/L2-hot, 20 KB per hk)
    f32x4 pv[4];
    #pragma unroll
    for (int ctd=0;ctd<4;ctd++) pv[ctd] = (f32x4)0.f;
    #pragma unroll
    for (int ks=0;ks<5;ks++){
        int arow = w*16 + c;
        short8v pf = *(short8v*)(pl + SWZ(arow*320 + ks*64 + lg*16, arow));
        #pragma unroll
        for (int ctd=0;ctd<4;ctd++){
            int row = ctd*16 + c;
            short8v bf = *(const short8v*)(cvhk + (size_t)row*160 + ks*32 + lg*8);
            pv[ctd] = MFMA(pf, bf, pv[ctd]);
        }
    }
    #pragma unroll
    for (int ctd=0;ctd<4;ctd++)
        #pragma unroll
        for (int reg=0;reg<4;reg++){
            int row = w*16 + lg*4 + reg;
            float inv = 1.0f/psl[row];
            int hh = hk*G + reg;
            int ii = i0 + (row>>2);
            outc[((size_t)(hh*NN + ii))*D + ctd*16 + c] = f2b(pv[ctd][reg]*inv);
        }
}

// ---------------------------------------------------------------------------
// selected-block attention, bf16 staging, lean LDS (17.4 KB). Block = (i, hk).
__global__ __launch_bounds__(256) void k_sel(
    const short* __restrict__ qb, const short* __restrict__ kbg, const short* __restrict__ vbg,
    const int* __restrict__ selidx, short* __restrict__ outf)
{
    __shared__ char ksl[64*128];
    __shared__ char vsl[64*128];
    __shared__ float ps[256];
    __shared__ int sel_s[4];
    int i = blockIdx.x, hk = blockIdx.y, t = threadIdx.x;
    if (t < 4) sel_s[t] = selidx[((size_t)(hk*NN + i))*NSEL + t];
    __syncthreads();
    for (int u=0;u<2;u++){
        int cid = t + 256*u; int row = cid>>3, ch = cid&7;
        int pos = sel_s[row>>4]*CB + (row&15);
        *(short8v*)(ksl + SWZ(row*128 + ch*16, row)) =
            *(const short8v*)(kbg + ((size_t)(hk*NN + pos))*D + ch*8);
        *(short8v*)(vsl + row*128 + ch*16) =
            *(const short8v*)(vbg + ((size_t)(hk*NN + pos))*D + ch*8);
    }
    int wv = t>>6, lane = t&63;
    short8v qv[8];
    {
        const short* qrow = qb + ((size_t)((hk*G + wv)*NN + i))*D;
        #pragma unroll
        for (int ch=0;ch<8;ch++) qv[ch] = *(const short8v*)(qrow + ch*8);
    }
    __syncthreads();
    int pos_l = sel_s[lane>>4]*CB + (lane&15);
    float s = 0.f;
    #pragma unroll
    for (int ch=0;ch<8;ch++){
        short8v kk = *(short8v*)(ksl + SWZ(lane*128 + ch*16, lane));
        #pragma unroll
        for (int e=0;e<8;e++) s += b2f(qv[ch][e]) * b2f(kk[e]);
    }
    s *= SCALE;
    if (pos_l > i) s = NEGV;
    float m = wave_max(s);
    float p = expf(s - m);
    float psum = wave_sum(p);
    ps[wv*64 + lane] = p;
    __syncthreads();
    int jg = lane>>4, dg = lane&15;
    float inv = 1.0f/psum;
    f32x4 partial = (f32x4)0.f;
    #pragma unroll
    for (int jj=0;jj<16;jj++){
        int j = jg*16 + jj;
        float pw = ps[wv*64 + j];
        short4v vv = *(short4v*)(vsl + j*128 + dg*8);
        partial[0] += pw*b2f(vv[0]); partial[1] += pw*b2f(vv[1]);
        partial[2] += pw*b2f(vv[2]); partial[3] += pw*b2f(vv[3]);
    }
    partial += shflx4(partial, 16);
    partial += shflx4(partial, 32);
    if (lane < 16){
        short4v r;
        r[0]=f2b(partial[0]*inv); r[1]=f2b(partial[1]*inv);
        r[2]=f2b(partial[2]*inv); r[3]=f2b(partial[3]*inv);
        *(short4v*)(outf + ((size_t)((hk*G+wv)*NN + i))*D + dg*4) = r;
    }
}

// ---------------------------------------------------------------------------
// fused: swin (blocks 0..511) + gates (512..639). LDS 41216 B (P aliases K tile).
__global__ __launch_bounds__(256) void k_swg(
    const short* __restrict__ qb, const short* __restrict__ kb16, const short* __restrict__ vT,
    short* __restrict__ outs,
    const short* __restrict__ hb, const short* __restrict__ cwb, float* __restrict__ gpart)
{
    __shared__ char smem[41216];
    int b = blockIdx.x, t = threadIdx.x;

    if (b < 512){
        char* aq = smem;                     // 8192
        char* kb = smem + 8192;              // 16384 (pl aliases after QK^T)
        char* vl = smem + 24576;             // 16384
        float* psl = (float*)(smem + 40960); // 256
        char* pl = kb;
        int i0 = (b & 31)*64, h = b >> 5;
        int hk = h >> 2;
        int pa = i0 - 64;
        for (int u=0;u<2;u++){
            int cid = t + 256*u; int row = cid>>3, ch = cid&7;
            *(short8v*)(aq + SWZ(row*128 + ch*16, row)) =
                *(const short8v*)(qb + ((size_t)(h*NN + i0 + row))*D + ch*8);
        }
        for (int u=0;u<4;u++){
            int cid = t + 256*u; int row = cid>>3, ch = cid&7;
            int pos = pa + row; pos = pos < 0 ? 0 : pos;
            *(short8v*)(kb + SWZ(row*128 + ch*16, row)) =
                *(const short8v*)(kb16 + ((size_t)(hk*NN + pos))*D + ch*8);
        }
        for (int u=0;u<4;u++){
            int cid = t + 256*u; int d = cid>>4, ch = cid&15;
            int ps0 = pa + ch*8;
            short8v val;
            const short* src = vT + ((size_t)(hk*64 + d))*NN + ps0;
            if (ps0 >= 0) val = *(const short8v*)src;
            else {
                #pragma unroll
                for (int e=0;e<8;e++){ int pp = ps0+e; pp = pp<0?0:pp; val[e] = vT[((size_t)(hk*64+d))*NN + pp]; }
            }
            *(short8v*)(vl + SWZ(d*256 + ch*16, d)) = val;
        }
        __syncthreads();
        int w = t>>6, lane = t&63, c = lane&15, lg = lane>>4;
        f32x4 acc[8];
        #pragma unroll
        for (int ct=0;ct<8;ct++) acc[ct] = (f32x4)0.f;
        #pragma unroll
        for (int ks=0;ks<2;ks++){
            int arow = w*16 + c;
            short8v af = *(short8v*)(aq + SWZ(arow*128 + ks*64 + lg*16, arow));
            #pragma unroll
            for (int ct=0;ct<8;ct++){
                int brow = ct*16 + c;
                short8v bf = *(short8v*)(kb + SWZ(brow*128 + ks*64 + lg*16, brow));
                acc[ct] = MFMA(af, bf, acc[ct]);
            }
        }
        #pragma unroll
        for (int ct=0;ct<8;ct++){
            int j = ct*16 + c;
            #pragma unroll
            for (int reg=0;reg<4;reg++){
                int tl = w*16 + lg*4 + reg;
                bool vis = (j >= tl+1) && (j <= tl+64) && (pa + j >= 0);
                float s = acc[ct][reg]*SCALE;
                acc[ct][reg] = vis ? s : NEGV;
            }
        }
        f32x4 mx = acc[0];
        #pragma unroll
        for (int ct=1;ct<8;ct++) mx = vmax4(mx, acc[ct]);
        #pragma unroll
        for (int o=1;o<16;o<<=1) mx = vmax4(mx, shflx4(mx,o));
        f32x4 sum = (f32x4)0.f;
        #pragma unroll
        for (int ct=0;ct<8;ct++){ acc[ct] = exp4(acc[ct]-mx); sum += acc[ct]; }
        #pragma unroll
        for (int o=1;o<16;o<<=1) sum += shflx4(sum,o);
        __syncthreads();
        #pragma unroll
        for (int ct=0;ct<8;ct++){
            #pragma unroll
            for (int reg=0;reg<4;reg++){
                int row = w*16 + lg*4 + reg;
                *(short*)(pl + SWZ(row*256 + (ct*16+c)*2, row)) = f2b(acc[ct][reg]);
            }
        }
        if (c==0){
            #pragma unroll
            for (int reg=0;reg<4;reg++) psl[w*16+lg*4+reg] = sum[reg];
        }
        __syncthreads();
        f32x4 pv[4];
        #pragma unroll
        for (int ctd=0;ctd<4;ctd++) pv[ctd] = (f32x4)0.f;
        #pragma unroll
        for (int ks=0;ks<4;ks++){
            int arow = w*16 + c;
            short8v pf = *(short8v*)(pl + SWZ(arow*256 + ks*64 + lg*16, arow));
            #pragma unroll
            for (int ctd=0;ctd<4;ctd++){
                int brow = ctd*16 + c;
                short8v bf = *(short8v*)(vl + SWZ(brow*256 + ks*64 + lg*16, brow));
                pv[ctd] = MFMA(pf, bf, pv[ctd]);
            }
        }
        #pragma unroll
        for (int ctd=0;ctd<4;ctd++)
            #pragma unroll
            for (int reg=0;reg<4;reg++){
                int row = w*16 + lg*4 + reg;
                float inv = 1.0f/psl[row];
                outs[((size_t)(h*NN + i0 + row))*D + ctd*16 + c] = f2b(pv[ctd][reg]*inv);
            }
        return;
    }
    {
        int idx = b - 512;
        char* ha = smem;
        char* bl = smem + 8192;
        int i0 = (idx & 31)*64, ky = idx >> 5;
        int w = t>>6, lane = t&63, c = lane&15, lg = lane>>4;
        f32x4 acc[3];
        #pragma unroll
        for (int ct=0;ct<3;ct++) acc[ct] = (f32x4)0.f;
        for (int kc=0;kc<4;kc++){
            int kbase = ky*256 + kc*64;
            if (kc) __syncthreads();
            for (int u=0;u<2;u++){
                int cid = t + 256*u; int row = cid>>3, ch = cid&7;
                *(short8v*)(ha + SWZ(row*128 + ch*16, row)) =
                    *(const short8v*)(hb + (size_t)(i0+row)*HID + kbase + ch*8);
            }
            for (int u=0;u<2;u++){
                int cid = t + 256*u;
                if (cid < 384){
                    int row = cid>>3, ch = cid&7;
                    *(short8v*)(bl + SWZ(row*128 + ch*16, row)) =
                        *(const short8v*)(cwb + (size_t)row*HID + kbase + ch*8);
                }
            }
            __syncthreads();
            #pragma unroll
            for (int ks=0;ks<2;ks++){
                int arow = w*16 + c;
                short8v af = *(short8v*)(ha + SWZ(arow*128 + ks*64 + lg*16, arow));
                #pragma unroll
                for (int ct=0;ct<3;ct++){
                    int brow = ct*16 + c;
                    short8v bf = *(short8v*)(bl + SWZ(brow*128 + ks*64 + lg*16, brow));
                    acc[ct] = MFMA(af, bf, acc[ct]);
                }
            }
        }
        #pragma unroll
        for (int ct=0;ct<3;ct++)
            #pragma unroll
            for (int reg=0;reg<4;reg++){
                int row = w*16 + lg*4 + reg;
                gpart[((size_t)ky*NN + i0 + row)*48 + ct*16 + c] = acc[ct][reg];
            }
    }
}

// ---------------------------------------------------------------------------
// gated combine -> comb bf16 [N][HID]
__global__ __launch_bounds__(256) void k_comb(
    const short* __restrict__ outc, const short* __restrict__ outf, const short* __restrict__ outs_,
    const float* __restrict__ gpart, const float* __restrict__ cb, short* __restrict__ comb)
{
    __shared__ float gs[48];
    int i = blockIdx.x, t = threadIdx.x;
    if (t < 48){
        float s = gpart[(size_t)0*NN*48 + i*48 + t] + gpart[(size_t)1*NN*48 + i*48 + t]
                + gpart[(size_t)2*NN*48 + i*48 + t] + gpart[(size_t)3*NN*48 + i*48 + t] + cb[t];
        gs[t] = 1.0f/(1.0f+expf(-s));
    }
    __syncthreads();
    int hh = t>>4, d0 = (t&15)*4;
    float g0 = gs[hh*3], g1 = gs[hh*3+1], g2 = gs[hh*3+2];
    size_t off = ((size_t)(hh*NN + i))*D + d0;
    short4v a = *(const short4v*)(outc + off);
    short4v b = *(const short4v*)(outf + off);
    short4v cc = *(const short4v*)(outs_ + off);
    short4v r;
    #pragma unroll
    for (int e=0;e<4;e++) r[e] = f2b(g0*b2f(a[e]) + g1*b2f(b[e]) + g2*b2f(cc[e]));
    *(short4v*)(comb + (size_t)i*HID + t*4) = r;
}

// ---------------------------------------------------------------------------
// out = comb (bf16 2048x1024) @ wb^T (bf16 1024x1024), f32 out. 64x64 tile, dbuf.
__global__ __launch_bounds__(256) void k_gemm(
    const short* __restrict__ A, const short* __restrict__ Bw, float* __restrict__ out)
{
    __shared__ char ab[2][64*128];
    __shared__ char bb[2][64*128];
    int m0 = blockIdx.x*64, n0 = blockIdx.y*64, t = threadIdx.x;
    int w = t>>6, lane = t&63, c = lane&15, lg = lane>>4;
    int r0 = t>>3, ch0 = t&7;
    f32x4 acc[4];
    #pragma unroll
    for (int ct=0;ct<4;ct++) acc[ct] = (f32x4)0.f;
    const short* Ap = A  + (size_t)(m0+r0)*HID + ch0*8;
    const short* Bp = Bw + (size_t)(n0+r0)*HID + ch0*8;
    short8v ra0 = *(const short8v*)(Ap);
    short8v ra1 = *(const short8v*)(Ap + 32*HID);
    short8v rb0 = *(const short8v*)(Bp);
    short8v rb1 = *(const short8v*)(Bp + 32*HID);
    for (int kc=0;kc<16;kc++){
        char* abuf = ab[kc&1];
        char* bbuf = bb[kc&1];
        *(short8v*)(abuf + SWZ(r0*128 + ch0*16, r0)) = ra0;
        *(short8v*)(abuf + SWZ((r0+32)*128 + ch0*16, r0+32)) = ra1;
        *(short8v*)(bbuf + SWZ(r0*128 + ch0*16, r0)) = rb0;
        *(short8v*)(bbuf + SWZ((r0+32)*128 + ch0*16, r0+32)) = rb1;
        __syncthreads();
        if (kc < 15){
            const short* Ap2 = Ap + (kc+1)*64;
            const short* Bp2 = Bp + (kc+1)*64;
            ra0 = *(const short8v*)(Ap2);
            ra1 = *(const short8v*)(Ap2 + 32*HID);
            rb0 = *(const short8v*)(Bp2);
            rb1 = *(const short8v*)(Bp2 + 32*HID);
        }
        #pragma unroll
        for (int ks=0;ks<2;ks++){
            int arow = w*16 + c;
            short8v af = *(short8v*)(abuf + SWZ(arow*128 + ks*64 + lg*16, arow));
            #pragma unroll
            for (int ct=0;ct<4;ct++){
                int brow = ct*16 + c;
                short8v bf = *(short8v*)(bbuf + SWZ(brow*128 + ks*64 + lg*16, brow));
                acc[ct] = MFMA(af, bf, acc[ct]);
            }
        }
    }
    #pragma unroll
    for (int ct=0;ct<4;ct++)
        #pragma unroll
        for (int reg=0;reg<4;reg++){
            int row = w*16 + lg*4 + reg;
            out[((size_t)(m0+row))*HID + n0 + ct*16 + c] = acc[ct][reg];
        }
}

// ---------------------------------------------------------------------------
extern "C" void kernel_launch(void* const* d_in, const int* in_sizes, int n_in,
                              void* d_out, int out_size, void* d_ws, size_t ws_size,
                              hipStream_t stream)
{
    const float* hidden     = (const float*)d_in[0];
    const float* q          = (const float*)d_in[1];
    const float* k          = (const float*)d_in[2];
    const float* v          = (const float*)d_in[3];
    const float* memkv      = (const float*)d_in[4];
    const float* ksc        = (const float*)d_in[5];
    const float* vsc        = (const float*)d_in[6];
    const float* combiner_w = (const float*)d_in[7];
    const float* combiner_b = (const float*)d_in[8];
    const float* combine_w  = (const float*)d_in[9];
    float* out = (float*)d_out;

    char* p = (char*)d_ws;
    short* ckb  = (short*)p; p += (size_t)HKV*144*64*2;
    short* cvtg = (short*)p; p += (size_t)HKV*64*160*2;
    short* qbg  = (short*)p; p += (size_t)H*NN*D*2;
    short* hbg  = (short*)p; p += (size_t)NN*HID*2;
    short* wbg  = (short*)p; p += (size_t)HID*HID*2;
    short* cwbg = (short*)p; p += (size_t)48*HID*2;
    short* kbg  = (short*)p; p += (size_t)HKV*NN*D*2;
    short* vbg  = (short*)p; p += (size_t)HKV*NN*D*2;
    short* vTg  = (short*)p; p += (size_t)HKV*64*NN*2;
    short* outc = (short*)p; p += (size_t)H*NN*D*2;
    short* outf = (short*)p; p += (size_t)H*NN*D*2;
    short* outs = (short*)p; p += (size_t)H*NN*D*2;
    float* gpart= (float*)p; p += (size_t)4*NN*48*4;
    short* comb = (short*)p; p += (size_t)NN*HID*2;
    int*  selix = (int*)p;   p += (size_t)HKV*NN*NSEL*4;

    k_prep  <<<5968, 256, 0, stream>>>(q, hidden, combine_w, combiner_w, k, v,
                                        memkv, ksc, vsc,
                                        qbg, hbg, wbg, cwbg, kbg, vbg, vTg, ckb, cvtg);
    k_cattn <<<dim3(NN/16, HKV), 256, 0, stream>>>(qbg, ckb, cvtg, outc, selix);
    k_swg   <<<640, 256, 0, stream>>>(qbg, kbg, vTg, outs, hbg, cwbg, gpart);
    k_sel   <<<dim3(NN, HKV), 256, 0, stream>>>(qbg, kbg, vbg, selix, outf);
    k_comb  <<<NN, 256, 0, stream>>>(outc, outf, outs, gpart, combiner_b, comb);
    k_gemm  <<<dim3(NN/64, HID/64), 256, 0, stream>>>(comb, wbg, out);
}

// Round 8
// 79.002 us; speedup vs baseline: 1.3156x; 1.0258x over previous
//
#include <hip/hip_runtime.h>
#include <hip/hip_bf16.h>
#include <math.h>

#define H    16
#define HKV  4
#define G    4
#define NN   2048
#define D    64
#define HID  1024
#define CB   16
#define W    128
#define NSEL 4
#define WIN  64
#define NEGV -1e10f
#define SCALE 0.125f

typedef __attribute__((ext_vector_type(4))) float f32x4;
typedef __attribute__((ext_vector_type(4))) short short4v;
typedef __attribute__((ext_vector_type(8))) short short8v;

__device__ inline short f2b(float x){
    __hip_bfloat16 h = __float2bfloat16(x);
    return *reinterpret_cast<short*>(&h);
}
__device__ inline float b2f(short s){
    unsigned u = ((unsigned)(unsigned short)s) << 16;
    return __builtin_bit_cast(float, u);
}
__device__ inline short8v cvt8(f32x4 a, f32x4 b){
    short8v r;
    r[0]=f2b(a[0]); r[1]=f2b(a[1]); r[2]=f2b(a[2]); r[3]=f2b(a[3]);
    r[4]=f2b(b[0]); r[5]=f2b(b[1]); r[6]=f2b(b[2]); r[7]=f2b(b[3]);
    return r;
}
#define SWZ(byte, row) ((byte) ^ (((row)&7)<<4))
#define MFMA(a,b,c) __builtin_amdgcn_mfma_f32_16x16x32_bf16(a,b,c,0,0,0)

__device__ inline float wave_sum(float x){ for(int o=32;o;o>>=1) x += __shfl_xor(x,o); return x; }
__device__ inline float wave_max(float x){ for(int o=32;o;o>>=1) x = fmaxf(x,__shfl_xor(x,o)); return x; }

__device__ inline f32x4 vmax4(f32x4 a, f32x4 b){
    f32x4 r; r[0]=fmaxf(a[0],b[0]); r[1]=fmaxf(a[1],b[1]); r[2]=fmaxf(a[2],b[2]); r[3]=fmaxf(a[3],b[3]); return r;
}
__device__ inline f32x4 shflx4(f32x4 x, int o){
    f32x4 r; r[0]=__shfl_xor(x[0],o); r[1]=__shfl_xor(x[1],o); r[2]=__shfl_xor(x[2],o); r[3]=__shfl_xor(x[3],o); return r;
}
__device__ inline f32x4 exp4(f32x4 x){
    f32x4 r; r[0]=expf(x[0]); r[1]=expf(x[1]); r[2]=expf(x[2]); r[3]=expf(x[3]); return r;
}

// ---------------------------------------------------------------------------
// fused prep: combine_w/combiner_w/k converts + V transpose + compressed KV.
__device__ inline void conv_seg(const float* __restrict__ src, short* __restrict__ dst,
                                int b, int t){
    size_t idx = (size_t)b*1024 + t*4;
    f32x4 a = *(const f32x4*)(src + idx);
    short4v r; r[0]=f2b(a[0]); r[1]=f2b(a[1]); r[2]=f2b(a[2]); r[3]=f2b(a[3]);
    *(short4v*)(dst + idx) = r;
}

__global__ __launch_bounds__(256) void k_prep(
    const float* __restrict__ combine_w, const float* __restrict__ combiner_w,
    const float* __restrict__ k, const float* __restrict__ v,
    const float* __restrict__ memkv, const float* __restrict__ ksc, const float* __restrict__ vsc,
    short* __restrict__ wb, short* __restrict__ cwb, short* __restrict__ kb16,
    short* __restrict__ vT, short* __restrict__ ckb, short* __restrict__ cvtg)
{
    int b = blockIdx.x, t = threadIdx.x;
    if (b < 1024){ conv_seg(combine_w, wb, b, t); return; }
    b -= 1024;
    if (b < 48){ conv_seg(combiner_w, cwb, b, t); return; }
    b -= 48;
    if (b < 512){ conv_seg(k, kb16, b, t); return; }
    b -= 512;
    if (b < 128){
        // V transpose (emit vT)
        __shared__ float tl[64][65];
        int hk = b>>5, i0 = (b&31)*64;
        for (int u=0;u<4;u++){
            int cid = t + 256*u; int r = cid>>4, ch = cid&15;
            f32x4 a = *(const f32x4*)(v + ((size_t)(hk*NN + i0 + r))*D + ch*4);
            tl[r][ch*4+0]=a[0]; tl[r][ch*4+1]=a[1]; tl[r][ch*4+2]=a[2]; tl[r][ch*4+3]=a[3];
        }
        __syncthreads();
        int d = t>>2, qd = t&3;
        short8v p0, p1;
        #pragma unroll
        for (int e=0;e<8;e++) p0[e] = f2b(tl[qd*16+e][d]);
        #pragma unroll
        for (int e=0;e<8;e++) p1[e] = f2b(tl[qd*16+8+e][d]);
        short* dst = vT + ((size_t)(hk*64 + d))*NN + i0 + qd*16;
        *(short8v*)dst = p0;
        *(short8v*)(dst+8) = p1;
        return;
    }
    b -= 128;
    {
        int j = b;
        int hk = t>>6, d = t&63;
        if (j > 128){
            if (j < 144) ckb[((size_t)(hk*144 + j))*64 + d] = 0;
            cvtg[((size_t)(hk*64 + d))*160 + j] = 0;
            return;
        }
        float xk, xv;
        if (j==0){ xk = memkv[(0*HKV+hk)*D + d]; xv = memkv[(HKV+hk)*D + d]; }
        else {
            int jb = j-1;
            const float* kp = k + ((size_t)(hk*NN + jb*CB))*D + d;
            const float* vp = v + ((size_t)(hk*NN + jb*CB))*D + d;
            float sk=0.f, sv=0.f;
            #pragma unroll
            for (int tt=0;tt<CB;tt++){ sk += kp[tt*D]; sv += vp[tt*D]; }
            xk = sk*(1.0f/CB); xv = sv*(1.0f/CB);
            float msk = wave_sum(xk*xk)*(1.0f/D);
            float msv = wave_sum(xv*xv)*(1.0f/D);
            xk = xk*rsqrtf(msk+1e-6f)*ksc[d];
            xv = xv*rsqrtf(msv+1e-6f)*vsc[d];
        }
        ckb[((size_t)(hk*144 + j))*64 + d] = f2b(xk);
        cvtg[((size_t)(hk*64 + d))*160 + j] = f2b(xv);
    }
}

// ---------------------------------------------------------------------------
// compressed attention + importance + top-k. Block = (hk, 16 tokens), 4 waves.
// LDS 35072 B static (P aliases aq/ckl; CV^T read direct from L1/L2; Q cvt inline).
__global__ __launch_bounds__(256) void k_cattn(
    const float* __restrict__ q, const short* __restrict__ ckb, const short* __restrict__ cvt_g,
    short* __restrict__ outc, int* __restrict__ selidx)
{
    __shared__ char smem[35072];
    char* aq  = smem;                      // 64*128 = 8192
    char* ckl = smem + 8192;               // 144*128 = 18432 (ends 26624)
    char* pl  = smem;                      // alias: 64*320 = 20480 <= 26624
    float* impl = (float*)(smem + 26624);  // 16*128 f32
    float* psl  = (float*)(smem + 34816);  // 64 f32
    int i0 = blockIdx.x*16, hk = blockIdx.y, t = threadIdx.x;
    const short* cvhk = cvt_g + (size_t)hk*64*160;

    for (int u=0;u<2;u++){
        int cid = t + 256*u; int row = cid>>3, ch = cid&7;
        const float* src = q + ((size_t)((hk*G + (row&3))*NN + i0 + (row>>2)))*D + ch*8;
        f32x4 a = *(const f32x4*)src, bb2 = *(const f32x4*)(src+4);
        *(short8v*)(aq + SWZ(row*128 + ch*16, row)) = cvt8(a,bb2);
    }
    for (int u=0;u<5;u++){
        int cid = t + 256*u;
        if (cid < 1152){
            int row = cid>>3, ch = cid&7;
            const short* src = ckb + ((size_t)(hk*144 + row))*64 + ch*8;
            *(short8v*)(ckl + SWZ(row*128 + ch*16, row)) = *(const short8v*)src;
        }
    }
    __syncthreads();

    int w = t>>6, lane = t&63, c = lane&15, lg = lane>>4;
    f32x4 acc[9];
    #pragma unroll
    for (int ct=0;ct<9;ct++) acc[ct] = (f32x4)0.f;

    #pragma unroll
    for (int ks=0;ks<2;ks++){
        int arow = w*16 + c;
        short8v af = *(short8v*)(aq + SWZ(arow*128 + ks*64 + lg*16, arow));
        #pragma unroll
        for (int ct=0;ct<9;ct++){
            int row = ct*16 + c;
            short8v bf = *(short8v*)(ckl + SWZ(row*128 + ks*64 + lg*16, row));
            acc[ct] = MFMA(af, bf, acc[ct]);
        }
    }

    f32x4 sum;
    {
        int tloc = w*4 + lg;
        int ii = i0 + tloc;
        #pragma unroll
        for (int ct=0;ct<9;ct++){
            int j = ct*16 + c;
            bool vis = (j==0) || (j<=128 && j*16 <= ii);
            f32x4 s = acc[ct]*SCALE;
            if (!vis){ s[0]=NEGV; s[1]=NEGV; s[2]=NEGV; s[3]=NEGV; }
            acc[ct] = s;
        }
        #pragma unroll
        for (int ct=0;ct<9;ct++){
            int j = ct*16 + c;
            if (j>=1 && j<=128){
                f32x4 s = acc[ct];
                impl[tloc*128 + (j-1)] = 0.25f*(s[0]+s[1]+s[2]+s[3]);
            }
        }
        f32x4 mx = acc[0];
        #pragma unroll
        for (int ct=1;ct<9;ct++) mx = vmax4(mx, acc[ct]);
        #pragma unroll
        for (int o=1;o<16;o<<=1) mx = vmax4(mx, shflx4(mx,o));
        sum = (f32x4)0.f;
        #pragma unroll
        for (int ct=0;ct<9;ct++){ acc[ct] = exp4(acc[ct]-mx); sum += acc[ct]; }
        #pragma unroll
        for (int o=1;o<16;o<<=1) sum += shflx4(sum,o);
    }
    __syncthreads();

    #pragma unroll
    for (int ct=0;ct<9;ct++){
        #pragma unroll
        for (int reg=0;reg<4;reg++){
            int row = w*16 + lg*4 + reg;
            *(short*)(pl + SWZ(row*320 + (ct*16+c)*2, row)) = f2b(acc[ct][reg]);
        }
    }
    #pragma unroll
    for (int reg=0;reg<4;reg++){
        int row = w*16 + lg*4 + reg;
        *(short*)(pl + SWZ(row*320 + (144+c)*2, row)) = 0;
    }
    if (c==0){
        #pragma unroll
        for (int reg=0;reg<4;reg++) psl[w*16 + lg*4 + reg] = sum[reg];
    }
    __syncthreads();

    #pragma unroll 1
    for (int s4=0;s4<4;s4++){
        int tt = w*4 + s4;
        float v0 = impl[tt*128 + lane];
        float v1 = impl[tt*128 + 64 + lane];
        int sel[4];
        #pragma unroll
        for (int r4=0;r4<4;r4++){
            float bv; int bj;
            if (v1 > v0){ bv=v1; bj=lane+64; } else { bv=v0; bj=lane; }
            #pragma unroll
            for (int o=32;o;o>>=1){
                float ov = __shfl_xor(bv,o);
                int oj = __shfl_xor(bj,o);
                if (ov > bv || (ov==bv && oj<bj)){ bv=ov; bj=oj; }
            }
            sel[r4]=bj;
            if (bj==lane) v0 = -INFINITY;
            else if (bj==lane+64) v1 = -INFINITY;
        }
        if (lane==0){
            int* sp = selidx + ((size_t)(hk*NN + i0 + tt))*NSEL;
            sp[0]=sel[0]; sp[1]=sel[1]; sp[2]=sel[2]; sp[3]=sel[3];
        }
    }

    f32x4 pv[4];
    #pragma unroll
    for (int ctd=0;ctd<4;ctd++) pv[ctd] = (f32x4)0.f;
    #pragma unroll
    for (int ks=0;ks<5;ks++){
        int arow = w*16 + c;
        short8v pf = *(short8v*)(pl + SWZ(arow*320 + ks*64 + lg*16, arow));
        #pragma unroll
        for (int ctd=0;ctd<4;ctd++){
            int row = ctd*16 + c;
            short8v bf = *(const short8v*)(cvhk + (size_t)row*160 + ks*32 + lg*8);
            pv[ctd] = MFMA(pf, bf, pv[ctd]);
        }
    }
    #pragma unroll
    for (int ctd=0;ctd<4;ctd++)
        #pragma unroll
        for (int reg=0;reg<4;reg++){
            int row = w*16 + lg*4 + reg;
            float inv = 1.0f/psl[row];
            int hh = hk*G + reg;
            int ii = i0 + (row>>2);
            outc[((size_t)(hh*NN + ii))*D + ctd*16 + c] = f2b(pv[ctd][reg]*inv);
        }
}

// ---------------------------------------------------------------------------
// selected-block attention via MFMA (M=16, 4 valid head-rows). One wave per (i,hk).
// K and V^T fragments loaded directly from L2-hot global; only P goes through LDS.
__global__ __launch_bounds__(256) void k_sel(
    const float* __restrict__ q, const short* __restrict__ kbg, const short* __restrict__ vTg,
    const int* __restrict__ selidx, short* __restrict__ outf)
{
    __shared__ short pls[4][4*64];   // per-wave P[head][key]
    int i0 = blockIdx.x*4, hk = blockIdx.y, t = threadIdx.x;
    int wv = t>>6, lane = t&63;
    int i = i0 + wv;
    int c = lane&15, lg = lane>>4;
    int head = c & 3;

    int sel_r[4];
    #pragma unroll
    for (int nt=0;nt<4;nt++) sel_r[nt] = selidx[((size_t)(hk*NN + i))*NSEL + nt];

    // Q A-frags (2 ksteps), f32 -> bf16, row = head (clamped)
    short8v qa[2];
    #pragma unroll
    for (int ks=0;ks<2;ks++){
        const float* src = q + ((size_t)((hk*G + head)*NN + i))*D + ks*32 + lg*8;
        f32x4 a = *(const f32x4*)src, b = *(const f32x4*)(src+4);
        qa[ks] = cvt8(a,b);
    }

    // QK^T: acc[nt][reg] = sim[head=reg][key=nt*16+c] (valid lanes 0-15)
    f32x4 acc[4];
    #pragma unroll
    for (int nt=0;nt<4;nt++) acc[nt] = (f32x4)0.f;
    #pragma unroll
    for (int ks=0;ks<2;ks++){
        #pragma unroll
        for (int nt=0;nt<4;nt++){
            int pos = sel_r[nt]*CB + c;
            short8v bf = *(const short8v*)(kbg + ((size_t)(hk*NN + pos))*D + ks*32 + lg*8);
            acc[nt] = MFMA(qa[ks], bf, acc[nt]);
        }
    }
    // scale + causal mask (per key column)
    #pragma unroll
    for (int nt=0;nt<4;nt++){
        int pos = sel_r[nt]*CB + c;
        f32x4 s = acc[nt]*SCALE;
        if (pos > i){ s[0]=NEGV; s[1]=NEGV; s[2]=NEGV; s[3]=NEGV; }
        acc[nt] = s;
    }
    // per-head softmax over 64 keys (reduce over nt, then lanes 0-15 group)
    f32x4 mx = acc[0];
    #pragma unroll
    for (int nt=1;nt<4;nt++) mx = vmax4(mx, acc[nt]);
    #pragma unroll
    for (int o=1;o<16;o<<=1) mx = vmax4(mx, shflx4(mx,o));
    f32x4 sum = (f32x4)0.f;
    #pragma unroll
    for (int nt=0;nt<4;nt++){ acc[nt] = exp4(acc[nt]-mx); sum += acc[nt]; }
    #pragma unroll
    for (int o=1;o<16;o<<=1) sum += shflx4(sum,o);

    // P -> LDS (bf16), lanes 0-15 hold all data
    if (lane < 16){
        #pragma unroll
        for (int nt=0;nt<4;nt++)
            #pragma unroll
            for (int reg=0;reg<4;reg++)
                pls[wv][reg*64 + nt*16 + lane] = f2b(acc[nt][reg]);
    }
    __syncthreads();

    // PV: out[head][d] = P(4x64) @ V(64x64); B-frag direct from vTg (V^T)
    f32x4 pv[4];
    #pragma unroll
    for (int nt=0;nt<4;nt++) pv[nt] = (f32x4)0.f;
    #pragma unroll
    for (int ks=0;ks<2;ks++){
        short8v pa = *(const short8v*)(&pls[wv][head*64 + ks*32 + lg*8]);
        int sb = ks*2 + (lg>>1);
        int pos0 = sel_r[sb]*CB + (lg&1)*8;
        #pragma unroll
        for (int nt=0;nt<4;nt++){
            int d = nt*16 + c;
            short8v bf = *(const short8v*)(vTg + ((size_t)(hk*64 + d))*NN + pos0);
            pv[nt] = MFMA(pa, bf, pv[nt]);
        }
    }
    if (lane < 16){
        f32x4 inv;
        inv[0]=1.f/sum[0]; inv[1]=1.f/sum[1]; inv[2]=1.f/sum[2]; inv[3]=1.f/sum[3];
        #pragma unroll
        for (int nt=0;nt<4;nt++)
            #pragma unroll
            for (int reg=0;reg<4;reg++)
                outf[((size_t)((hk*G+reg)*NN + i))*D + nt*16 + lane] = f2b(pv[nt][reg]*inv[reg]);
    }
}

// ---------------------------------------------------------------------------
// fused: swin (blocks 0..511) + gates (512..639). LDS 41216 B (P aliases K tile).
__global__ __launch_bounds__(256) void k_swg(
    const float* __restrict__ q, const short* __restrict__ kb16, const short* __restrict__ vT,
    short* __restrict__ outs,
    const float* __restrict__ hidden, const short* __restrict__ cwb, float* __restrict__ gpart)
{
    __shared__ char smem[41216];
    int b = blockIdx.x, t = threadIdx.x;

    if (b < 512){
        char* aq = smem;                     // 8192
        char* kb = smem + 8192;              // 16384 (pl aliases after QK^T)
        char* vl = smem + 24576;             // 16384
        float* psl = (float*)(smem + 40960); // 256
        char* pl = kb;
        int i0 = (b & 31)*64, h = b >> 5;
        int hk = h >> 2;
        int pa = i0 - 64;
        for (int u=0;u<2;u++){
            int cid = t + 256*u; int row = cid>>3, ch = cid&7;
            const float* src = q + ((size_t)(h*NN + i0 + row))*D + ch*8;
            f32x4 a = *(const f32x4*)src, bb2 = *(const f32x4*)(src+4);
            *(short8v*)(aq + SWZ(row*128 + ch*16, row)) = cvt8(a,bb2);
        }
        for (int u=0;u<4;u++){
            int cid = t + 256*u; int row = cid>>3, ch = cid&7;
            int pos = pa + row; pos = pos < 0 ? 0 : pos;
            *(short8v*)(kb + SWZ(row*128 + ch*16, row)) =
                *(const short8v*)(kb16 + ((size_t)(hk*NN + pos))*D + ch*8);
        }
        for (int u=0;u<4;u++){
            int cid = t + 256*u; int d = cid>>4, ch = cid&15;
            int ps0 = pa + ch*8;
            short8v val;
            const short* src = vT + ((size_t)(hk*64 + d))*NN + ps0;
            if (ps0 >= 0) val = *(const short8v*)src;
            else {
                #pragma unroll
                for (int e=0;e<8;e++){ int pp = ps0+e; pp = pp<0?0:pp; val[e] = vT[((size_t)(hk*64+d))*NN + pp]; }
            }
            *(short8v*)(vl + SWZ(d*256 + ch*16, d)) = val;
        }
        __syncthreads();
        int w = t>>6, lane = t&63, c = lane&15, lg = lane>>4;
        f32x4 acc[8];
        #pragma unroll
        for (int ct=0;ct<8;ct++) acc[ct] = (f32x4)0.f;
        #pragma unroll
        for (int ks=0;ks<2;ks++){
            int arow = w*16 + c;
            short8v af = *(short8v*)(aq + SWZ(arow*128 + ks*64 + lg*16, arow));
            #pragma unroll
            for (int ct=0;ct<8;ct++){
                int brow = ct*16 + c;
                short8v bf = *(short8v*)(kb + SWZ(brow*128 + ks*64 + lg*16, brow));
                acc[ct] = MFMA(af, bf, acc[ct]);
            }
        }
        #pragma unroll
        for (int ct=0;ct<8;ct++){
            int j = ct*16 + c;
            #pragma unroll
            for (int reg=0;reg<4;reg++){
                int tl = w*16 + lg*4 + reg;
                bool vis = (j >= tl+1) && (j <= tl+64) && (pa + j >= 0);
                float s = acc[ct][reg]*SCALE;
                acc[ct][reg] = vis ? s : NEGV;
            }
        }
        f32x4 mx = acc[0];
        #pragma unroll
        for (int ct=1;ct<8;ct++) mx = vmax4(mx, acc[ct]);
        #pragma unroll
        for (int o=1;o<16;o<<=1) mx = vmax4(mx, shflx4(mx,o));
        f32x4 sum = (f32x4)0.f;
        #pragma unroll
        for (int ct=0;ct<8;ct++){ acc[ct] = exp4(acc[ct]-mx); sum += acc[ct]; }
        #pragma unroll
        for (int o=1;o<16;o<<=1) sum += shflx4(sum,o);
        __syncthreads();
        #pragma unroll
        for (int ct=0;ct<8;ct++){
            #pragma unroll
            for (int reg=0;reg<4;reg++){
                int row = w*16 + lg*4 + reg;
                *(short*)(pl + SWZ(row*256 + (ct*16+c)*2, row)) = f2b(acc[ct][reg]);
            }
        }
        if (c==0){
            #pragma unroll
            for (int reg=0;reg<4;reg++) psl[w*16+lg*4+reg] = sum[reg];
        }
        __syncthreads();
        f32x4 pv[4];
        #pragma unroll
        for (int ctd=0;ctd<4;ctd++) pv[ctd] = (f32x4)0.f;
        #pragma unroll
        for (int ks=0;ks<4;ks++){
            int arow = w*16 + c;
            short8v pf = *(short8v*)(pl + SWZ(arow*256 + ks*64 + lg*16, arow));
            #pragma unroll
            for (int ctd=0;ctd<4;ctd++){
                int brow = ctd*16 + c;
                short8v bf = *(short8v*)(vl + SWZ(brow*256 + ks*64 + lg*16, brow));
                pv[ctd] = MFMA(pf, bf, pv[ctd]);
            }
        }
        #pragma unroll
        for (int ctd=0;ctd<4;ctd++)
            #pragma unroll
            for (int reg=0;reg<4;reg++){
                int row = w*16 + lg*4 + reg;
                float inv = 1.0f/psl[row];
                outs[((size_t)(h*NN + i0 + row))*D + ctd*16 + c] = f2b(pv[ctd][reg]*inv);
            }
        return;
    }
    {
        int idx = b - 512;
        char* ha = smem;
        char* bl = smem + 8192;
        int i0 = (idx & 31)*64, ky = idx >> 5;
        int w = t>>6, lane = t&63, c = lane&15, lg = lane>>4;
        f32x4 acc[3];
        #pragma unroll
        for (int ct=0;ct<3;ct++) acc[ct] = (f32x4)0.f;
        for (int kc=0;kc<4;kc++){
            int kbase = ky*256 + kc*64;
            if (kc) __syncthreads();
            for (int u=0;u<2;u++){
                int cid = t + 256*u; int row = cid>>3, ch = cid&7;
                const float* src = hidden + (size_t)(i0+row)*HID + kbase + ch*8;
                f32x4 a = *(const f32x4*)src, bb2 = *(const f32x4*)(src+4);
                *(short8v*)(ha + SWZ(row*128 + ch*16, row)) = cvt8(a,bb2);
            }
            for (int u=0;u<2;u++){
                int cid = t + 256*u;
                if (cid < 384){
                    int row = cid>>3, ch = cid&7;
                    *(short8v*)(bl + SWZ(row*128 + ch*16, row)) =
                        *(const short8v*)(cwb + (size_t)row*HID + kbase + ch*8);
                }
            }
            __syncthreads();
            #pragma unroll
            for (int ks=0;ks<2;ks++){
                int arow = w*16 + c;
                short8v af = *(short8v*)(ha + SWZ(arow*128 + ks*64 + lg*16, arow));
                #pragma unroll
                for (int ct=0;ct<3;ct++){
                    int brow = ct*16 + c;
                    short8v bf = *(short8v*)(bl + SWZ(brow*128 + ks*64 + lg*16, brow));
                    acc[ct] = MFMA(af, bf, acc[ct]);
                }
            }
        }
        #pragma unroll
        for (int ct=0;ct<3;ct++)
            #pragma unroll
            for (int reg=0;reg<4;reg++){
                int row = w*16 + lg*4 + reg;
                gpart[((size_t)ky*NN + i0 + row)*48 + ct*16 + c] = acc[ct][reg];
            }
    }
}

// ---------------------------------------------------------------------------
// gated combine -> comb bf16 [N][HID]
__global__ __launch_bounds__(256) void k_comb(
    const short* __restrict__ outc, const short* __restrict__ outf, const short* __restrict__ outs_,
    const float* __restrict__ gpart, const float* __restrict__ cb, short* __restrict__ comb)
{
    __shared__ float gs[48];
    int i = blockIdx.x, t = threadIdx.x;
    if (t < 48){
        float s = gpart[(size_t)0*NN*48 + i*48 + t] + gpart[(size_t)1*NN*48 + i*48 + t]
                + gpart[(size_t)2*NN*48 + i*48 + t] + gpart[(size_t)3*NN*48 + i*48 + t] + cb[t];
        gs[t] = 1.0f/(1.0f+expf(-s));
    }
    __syncthreads();
    int hh = t>>4, d0 = (t&15)*4;
    float g0 = gs[hh*3], g1 = gs[hh*3+1], g2 = gs[hh*3+2];
    size_t off = ((size_t)(hh*NN + i))*D + d0;
    short4v a = *(const short4v*)(outc + off);
    short4v b = *(const short4v*)(outf + off);
    short4v cc = *(const short4v*)(outs_ + off);
    short4v r;
    #pragma unroll
    for (int e=0;e<4;e++) r[e] = f2b(g0*b2f(a[e]) + g1*b2f(b[e]) + g2*b2f(cc[e]));
    *(short4v*)(comb + (size_t)i*HID + t*4) = r;
}

// ---------------------------------------------------------------------------
// out = comb (bf16 2048x1024) @ wb^T (bf16 1024x1024), f32 out. 64x64 tile, dbuf.
__global__ __launch_bounds__(256) void k_gemm(
    const short* __restrict__ A, const short* __restrict__ Bw, float* __restrict__ out)
{
    __shared__ char ab[2][64*128];
    __shared__ char bb[2][64*128];
    int m0 = blockIdx.x*64, n0 = blockIdx.y*64, t = threadIdx.x;
    int w = t>>6, lane = t&63, c = lane&15, lg = lane>>4;
    int r0 = t>>3, ch0 = t&7;
    f32x4 acc[4];
    #pragma unroll
    for (int ct=0;ct<4;ct++) acc[ct] = (f32x4)0.f;
    const short* Ap = A  + (size_t)(m0+r0)*HID + ch0*8;
    const short* Bp = Bw + (size_t)(n0+r0)*HID + ch0*8;
    short8v ra0 = *(const short8v*)(Ap);
    short8v ra1 = *(const short8v*)(Ap + 32*HID);
    short8v rb0 = *(const short8v*)(Bp);
    short8v rb1 = *(const short8v*)(Bp + 32*HID);
    for (int kc=0;kc<16;kc++){
        char* abuf = ab[kc&1];
        char* bbuf = bb[kc&1];
        *(short8v*)(abuf + SWZ(r0*128 + ch0*16, r0)) = ra0;
        *(short8v*)(abuf + SWZ((r0+32)*128 + ch0*16, r0+32)) = ra1;
        *(short8v*)(bbuf + SWZ(r0*128 + ch0*16, r0)) = rb0;
        *(short8v*)(bbuf + SWZ((r0+32)*128 + ch0*16, r0+32)) = rb1;
        __syncthreads();
        if (kc < 15){
            const short* Ap2 = Ap + (kc+1)*64;
            const short* Bp2 = Bp + (kc+1)*64;
            ra0 = *(const short8v*)(Ap2);
            ra1 = *(const short8v*)(Ap2 + 32*HID);
            rb0 = *(const short8v*)(Bp2);
            rb1 = *(const short8v*)(Bp2 + 32*HID);
        }
        #pragma unroll
        for (int ks=0;ks<2;ks++){
            int arow = w*16 + c;
            short8v af = *(short8v*)(abuf + SWZ(arow*128 + ks*64 + lg*16, arow));
            #pragma unroll
            for (int ct=0;ct<4;ct++){
                int brow = ct*16 + c;
                short8v bf = *(short8v*)(bbuf + SWZ(brow*128 + ks*64 + lg*16, brow));
                acc[ct] = MFMA(af, bf, acc[ct]);
            }
        }
    }
    #pragma unroll
    for (int ct=0;ct<4;ct++)
        #pragma unroll
        for (int reg=0;reg<4;reg++){
            int row = w*16 + lg*4 + reg;
            out[((size_t)(m0+row))*HID + n0 + ct*16 + c] = acc[ct][reg];
        }
}

// ---------------------------------------------------------------------------
extern "C" void kernel_launch(void* const* d_in, const int* in_sizes, int n_in,
                              void* d_out, int out_size, void* d_ws, size_t ws_size,
                              hipStream_t stream)
{
    const float* hidden     = (const float*)d_in[0];
    const float* q          = (const float*)d_in[1];
    const float* k          = (const float*)d_in[2];
    const float* v          = (const float*)d_in[3];
    const float* memkv      = (const float*)d_in[4];
    const float* ksc        = (const float*)d_in[5];
    const float* vsc        = (const float*)d_in[6];
    const float* combiner_w = (const float*)d_in[7];
    const float* combiner_b = (const float*)d_in[8];
    const float* combine_w  = (const float*)d_in[9];
    float* out = (float*)d_out;

    char* p = (char*)d_ws;
    short* ckb  = (short*)p; p += (size_t)HKV*144*64*2;
    short* cvtg = (short*)p; p += (size_t)HKV*64*160*2;
    short* wbg  = (short*)p; p += (size_t)HID*HID*2;
    short* cwbg = (short*)p; p += (size_t)48*HID*2;
    short* kbg  = (short*)p; p += (size_t)HKV*NN*D*2;
    short* vTg  = (short*)p; p += (size_t)HKV*64*NN*2;
    short* outc = (short*)p; p += (size_t)H*NN*D*2;
    short* outf = (short*)p; p += (size_t)H*NN*D*2;
    short* outs = (short*)p; p += (size_t)H*NN*D*2;
    float* gpart= (float*)p; p += (size_t)4*NN*48*4;
    short* comb = (short*)p; p += (size_t)NN*HID*2;
    int*  selix = (int*)p;   p += (size_t)HKV*NN*NSEL*4;

    k_prep  <<<1872, 256, 0, stream>>>(combine_w, combiner_w, k, v, memkv, ksc, vsc,
                                        wbg, cwbg, kbg, vTg, ckb, cvtg);
    k_cattn <<<dim3(NN/16, HKV), 256, 0, stream>>>(q, ckb, cvtg, outc, selix);
    k_swg   <<<640, 256, 0, stream>>>(q, kbg, vTg, outs, hidden, cwbg, gpart);
    k_sel   <<<dim3(NN/4, HKV), 256, 0, stream>>>(q, kbg, vTg, selix, outf);
    k_comb  <<<NN, 256, 0, stream>>>(outc, outf, outs, gpart, combiner_b, comb);
    k_gemm  <<<dim3(NN/64, HID/64), 256, 0, stream>>>(comb, wbg, out);
}